// Round 1
// baseline (1597.741 us; speedup 1.0000x reference)
//
#include <hip/hip_runtime.h>
#include <hip/hip_bf16.h>
#include <math.h>

typedef __attribute__((ext_vector_type(4))) float f32x4;
typedef __attribute__((ext_vector_type(8))) short s16x8;
typedef __attribute__((ext_vector_type(4))) short s16x4;
typedef __attribute__((ext_vector_type(4))) unsigned int u32x4;

static __device__ __forceinline__ unsigned short f2bf(float f) {
  unsigned int u = __builtin_bit_cast(unsigned int, f);
  u += 0x7FFFu + ((u >> 16) & 1u);           // RNE
  return (unsigned short)(u >> 16);
}
static __device__ __forceinline__ float bflo(unsigned int u) {
  return __builtin_bit_cast(float, u << 16);
}
static __device__ __forceinline__ float bfhi(unsigned int u) {
  return __builtin_bit_cast(float, u & 0xFFFF0000u);
}
static __device__ __forceinline__ float gelu_exact(float x) {
  return 0.5f * x * (1.0f + erff(x * 0.7071067811865475f));
}

// ---------------------------------------------------------------------------
// MFMA GEMM: C[M,N] = A[M,K] @ B[N,K]^T + bias   (fp32 in/out, bf16 MFMA)
// BM=64, BN=128, BK=64, 256 threads = 4 waves (2x2), wave tile 64x... (32x64)
// ---------------------------------------------------------------------------
#define GBM 64
#define GBN 128
#define GBK 64
#define GLDS 72   // +8 shorts pad -> 2-way-max bank aliasing on b128 frag reads

__global__ __launch_bounds__(256, 2)
void gemm_bias_kernel(const float* __restrict__ A, const float* __restrict__ Bw,
                      const float* __restrict__ bias, float* __restrict__ C,
                      int M, int N, int K) {
  __shared__ short As[GBM * GLDS];
  __shared__ short Bs[GBN * GLDS];
  const int tid = threadIdx.x;
  const int lane = tid & 63;
  const int wid = tid >> 6;
  const int wm = wid >> 1;              // 0..1 (row half)
  const int wn = wid & 1;               // 0..1 (col half)
  const int m0 = blockIdx.x * GBM;
  const int n0 = blockIdx.y * GBN;
  const int lr = lane & 15;             // fragment row (A) / col (B)
  const int lk = (lane >> 4) * 8;       // fragment k offset
  const bool kAligned = ((K & 3) == 0);

  f32x4 acc[2][4];
  #pragma unroll
  for (int i = 0; i < 2; ++i)
    #pragma unroll
    for (int j = 0; j < 4; ++j) acc[i][j] = (f32x4){0.f, 0.f, 0.f, 0.f};

  for (int k0 = 0; k0 < K; k0 += GBK) {
    __syncthreads();
    const bool fullK = kAligned && (k0 + GBK <= K);
    // stage A tile (64x64) fp32 -> bf16
    #pragma unroll
    for (int pass = 0; pass < 4; ++pass) {
      const int f = pass * 1024 + tid * 4;
      const int r = f >> 6, c = f & 63;
      f32x4 v = (f32x4){0.f, 0.f, 0.f, 0.f};
      const float* src = A + (size_t)(m0 + r) * K + (k0 + c);
      if (fullK) v = *(const f32x4*)src;
      else {
        #pragma unroll
        for (int i = 0; i < 4; ++i) if (k0 + c + i < K) v[i] = src[i];
      }
      s16x4 sv = { (short)f2bf(v[0]), (short)f2bf(v[1]), (short)f2bf(v[2]), (short)f2bf(v[3]) };
      *(s16x4*)&As[r * GLDS + c] = sv;
    }
    // stage B tile (128x64)
    #pragma unroll
    for (int pass = 0; pass < 8; ++pass) {
      const int f = pass * 1024 + tid * 4;
      const int r = f >> 6, c = f & 63;
      f32x4 v = (f32x4){0.f, 0.f, 0.f, 0.f};
      if (n0 + r < N) {
        const float* src = Bw + (size_t)(n0 + r) * K + (k0 + c);
        if (fullK) v = *(const f32x4*)src;
        else {
          #pragma unroll
          for (int i = 0; i < 4; ++i) if (k0 + c + i < K) v[i] = src[i];
        }
      }
      s16x4 sv = { (short)f2bf(v[0]), (short)f2bf(v[1]), (short)f2bf(v[2]), (short)f2bf(v[3]) };
      *(s16x4*)&Bs[r * GLDS + c] = sv;
    }
    __syncthreads();
    #pragma unroll
    for (int kk = 0; kk < GBK; kk += 32) {
      s16x8 af[2], bfr[4];
      #pragma unroll
      for (int m = 0; m < 2; ++m)
        af[m] = *(const s16x8*)&As[(wm * 32 + m * 16 + lr) * GLDS + kk + lk];
      #pragma unroll
      for (int n = 0; n < 4; ++n)
        bfr[n] = *(const s16x8*)&Bs[(wn * 64 + n * 16 + lr) * GLDS + kk + lk];
      #pragma unroll
      for (int m = 0; m < 2; ++m)
        #pragma unroll
        for (int n = 0; n < 4; ++n)
          acc[m][n] = __builtin_amdgcn_mfma_f32_16x16x32_bf16(af[m], bfr[n], acc[m][n], 0, 0, 0);
    }
  }
  // epilogue: C layout col=lane&15, row=(lane>>4)*4+i  (m89-verified)
  const int crow = (lane >> 4) * 4;
  #pragma unroll
  for (int m = 0; m < 2; ++m) {
    const int row = m0 + wm * 32 + m * 16 + crow;
    #pragma unroll
    for (int n = 0; n < 4; ++n) {
      const int col = n0 + wn * 64 + n * 16 + lr;
      if (col < N) {
        const float bv = bias[col];
        #pragma unroll
        for (int i = 0; i < 4; ++i)
          C[(size_t)(row + i) * N + col] = acc[m][n][i] + bv;
      }
    }
  }
}

// ---------------------------------------------------------------------------
// Row LayerNorm + exact GELU.  One 256-thread block per row, N in {256,512}.
// ---------------------------------------------------------------------------
__global__ __launch_bounds__(256)
void ln_gelu_kernel(const float* __restrict__ X, const float* __restrict__ g,
                    const float* __restrict__ bta, float* __restrict__ Y, int N) {
  const int row = blockIdx.x;
  const float* xr = X + (size_t)row * N;
  float* yr = Y + (size_t)row * N;
  const int tid = threadIdx.x;
  const float e0 = xr[tid];
  float e1 = 0.f;
  const bool two = (N > 256);
  if (two) e1 = xr[tid + 256];
  float s = e0 + e1;
  float ss = e0 * e0 + e1 * e1;
  #pragma unroll
  for (int off = 1; off < 64; off <<= 1) {
    s  += __shfl_xor(s, off);
    ss += __shfl_xor(ss, off);
  }
  __shared__ float red[8];
  const int w = tid >> 6;
  if ((tid & 63) == 0) { red[w] = s; red[4 + w] = ss; }
  __syncthreads();
  s  = red[0] + red[1] + red[2] + red[3];
  ss = red[4] + red[5] + red[6] + red[7];
  const float invN = 1.0f / (float)N;
  const float mean = s * invN;
  const float var = ss * invN - mean * mean;
  const float rstd = rsqrtf(var + 1e-5f);
  {
    const float z = (e0 - mean) * rstd * g[tid] + bta[tid];
    yr[tid] = gelu_exact(z);
  }
  if (two) {
    const float z = (e1 - mean) * rstd * g[tid + 256] + bta[tid + 256];
    yr[tid + 256] = gelu_exact(z);
  }
}

// ---------------------------------------------------------------------------
// w_sum = softmax(logits_g) + softmax(logits_p), rows of 82. wave per row.
// ---------------------------------------------------------------------------
__global__ __launch_bounds__(256)
void softmax2_kernel(const float* __restrict__ la, const float* __restrict__ lp,
                     float* __restrict__ w, int B) {
  const int wid = threadIdx.x >> 6;
  const int lane = threadIdx.x & 63;
  const int row = blockIdx.x * 4 + wid;
  if (row >= B) return;
  const bool has2 = (lane < 18);
  const float* a = la + (size_t)row * 82;
  const float* p = lp + (size_t)row * 82;
  float a0 = a[lane], a1 = has2 ? a[64 + lane] : -1e30f;
  float m = fmaxf(a0, a1);
  #pragma unroll
  for (int off = 1; off < 64; off <<= 1) m = fmaxf(m, __shfl_xor(m, off));
  float ea0 = __expf(a0 - m);
  float ea1 = has2 ? __expf(a1 - m) : 0.f;
  float sa = ea0 + ea1;
  #pragma unroll
  for (int off = 1; off < 64; off <<= 1) sa += __shfl_xor(sa, off);
  float p0 = p[lane], p1 = has2 ? p[64 + lane] : -1e30f;
  float mp = fmaxf(p0, p1);
  #pragma unroll
  for (int off = 1; off < 64; off <<= 1) mp = fmaxf(mp, __shfl_xor(mp, off));
  float ep0 = __expf(p0 - mp);
  float ep1 = has2 ? __expf(p1 - mp) : 0.f;
  float sp = ep0 + ep1;
  #pragma unroll
  for (int off = 1; off < 64; off <<= 1) sp += __shfl_xor(sp, off);
  const float ia = 1.0f / sa, ip = 1.0f / sp;
  w[(size_t)row * 82 + lane] = ea0 * ia + ep0 * ip;
  if (has2) w[(size_t)row * 82 + 64 + lane] = ea1 * ia + ep1 * ip;
}

// ---------------------------------------------------------------------------
// Fused 2-layer post-norm TransformerEncoder. thread = (seq,token), 3 seqs /
// 256-thread block (246 active lanes). X rows fp32 in LDS (stride 28 floats,
// 16B-aligned, 2-way max bank alias), K/V rows packed bf16 (stride 16 dwords).
// All weight reads are wave-uniform -> s_load. Row 246 = dump row for lanes
// 246..255 (keeps control flow uniform so scalar loads stay scalar).
// Attention: exp without max-subtract (logits ~O(0.01) by construction).
// ---------------------------------------------------------------------------
__global__ __launch_bounds__(256, 2)
void encoder_kernel(const float* __restrict__ w_sum,
                    const float* __restrict__ pathway, const float* __restrict__ misc,
                    const float* __restrict__ wqkv, const float* __restrict__ bqkv,
                    const float* __restrict__ wo, const float* __restrict__ bo,
                    const float* __restrict__ lg1, const float* __restrict__ lb1,
                    const float* __restrict__ fw1, const float* __restrict__ fb1,
                    const float* __restrict__ fw2, const float* __restrict__ fb2,
                    const float* __restrict__ lg2, const float* __restrict__ lb2,
                    float* __restrict__ out, int Btot) {
  __shared__ float Xs[(3 * 82 + 1) * 28];
  __shared__ unsigned int Ks[(3 * 82 + 1) * 16];
  __shared__ unsigned int Vs[(3 * 82 + 1) * 16];

  const int tid = threadIdx.x;
  const bool active = (tid < 246);
  const int rowW = active ? tid : 246;          // write row (246 = dump)
  int ls = tid / 82; if (ls > 2) ls = 2;        // local sequence (clamped)
  const int t = active ? (tid - ls * 82) : 0;   // token
  const int b = blockIdx.x * 3 + ls;
  const bool storeOK = active && (b < Btot);
  const int bb = (b < Btot) ? b : (Btot - 1);

  // Phase 0: acts[t] = (gene_w+prot_w)[t] * all_tokens[t]
  {
    const float* trow = (t < 50) ? (pathway + t * 24) : (misc + (t - 50) * 24);
    const float wv = w_sum[(size_t)bb * 82 + t];
    #pragma unroll
    for (int d = 0; d < 24; ++d) Xs[rowW * 28 + d] = wv * trow[d];
  }
  __syncthreads();

  float xf[24];
  #pragma unroll 1
  for (int layer = 0; layer < 2; ++layer) {
    const float* Wq = wqkv + layer * 72 * 24;
    const float* Bq = bqkv + layer * 72;

    // ---- Phase 1: QKV ----
    float x[24];
    {
      const float* xr = &Xs[(ls * 82 + t) * 28];
      #pragma unroll
      for (int d4 = 0; d4 < 6; ++d4) {
        f32x4 v = *(const f32x4*)(xr + 4 * d4);
        x[4*d4+0] = v[0]; x[4*d4+1] = v[1]; x[4*d4+2] = v[2]; x[4*d4+3] = v[3];
      }
    }
    float q[24];
    #pragma unroll
    for (int j = 0; j < 24; ++j) {
      float s = Bq[j];
      const float* wr = Wq + j * 24;
      #pragma unroll
      for (int kd = 0; kd < 24; ++kd) s = fmaf(wr[kd], x[kd], s);
      q[j] = s * 0.40824829046386302f;   // 1/sqrt(6) folded into q
    }
    {
      unsigned int pk[12];
      #pragma unroll
      for (int j2 = 0; j2 < 12; ++j2) {          // K rows (24..47)
        float s0 = Bq[24 + 2*j2], s1 = Bq[25 + 2*j2];
        const float* w0 = Wq + (24 + 2*j2) * 24;
        #pragma unroll
        for (int kd = 0; kd < 24; ++kd) {
          s0 = fmaf(w0[kd], x[kd], s0);
          s1 = fmaf(w0[24 + kd], x[kd], s1);
        }
        pk[j2] = (unsigned int)f2bf(s0) | ((unsigned int)f2bf(s1) << 16);
      }
      #pragma unroll
      for (int u = 0; u < 3; ++u) {
        u32x4 st = { pk[4*u], pk[4*u+1], pk[4*u+2], pk[4*u+3] };
        *(u32x4*)&Ks[rowW * 16 + 4*u] = st;
      }
      #pragma unroll
      for (int j2 = 0; j2 < 12; ++j2) {          // V rows (48..71)
        float s0 = Bq[48 + 2*j2], s1 = Bq[49 + 2*j2];
        const float* w0 = Wq + (48 + 2*j2) * 24;
        #pragma unroll
        for (int kd = 0; kd < 24; ++kd) {
          s0 = fmaf(w0[kd], x[kd], s0);
          s1 = fmaf(w0[24 + kd], x[kd], s1);
        }
        pk[j2] = (unsigned int)f2bf(s0) | ((unsigned int)f2bf(s1) << 16);
      }
      #pragma unroll
      for (int u = 0; u < 3; ++u) {
        u32x4 st = { pk[4*u], pk[4*u+1], pk[4*u+2], pk[4*u+3] };
        *(u32x4*)&Vs[rowW * 16 + 4*u] = st;
      }
    }
    __syncthreads();

    // ---- Phase 2: attention (4 heads x 6 dims), K/V rows broadcast ----
    float acc_o[24];
    float lsum[4] = {0.f, 0.f, 0.f, 0.f};
    #pragma unroll
    for (int d = 0; d < 24; ++d) acc_o[d] = 0.f;
    const unsigned int* Kb = &Ks[ls * 82 * 16];
    const unsigned int* Vb = &Vs[ls * 82 * 16];
    #pragma unroll 1
    for (int kp = 0; kp < 82; ++kp) {
      const unsigned int* kr = Kb + kp * 16;
      u32x4 ka = *(const u32x4*)(kr);
      u32x4 kb2 = *(const u32x4*)(kr + 4);
      u32x4 kc = *(const u32x4*)(kr + 8);
      unsigned int ku[12] = {ka[0],ka[1],ka[2],ka[3], kb2[0],kb2[1],kb2[2],kb2[3], kc[0],kc[1],kc[2],kc[3]};
      float kkv[24];
      #pragma unroll
      for (int i = 0; i < 12; ++i) { kkv[2*i] = bflo(ku[i]); kkv[2*i+1] = bfhi(ku[i]); }
      float p4[4];
      #pragma unroll
      for (int h = 0; h < 4; ++h) {
        float s = q[h*6] * kkv[h*6];
        #pragma unroll
        for (int dh = 1; dh < 6; ++dh) s = fmaf(q[h*6+dh], kkv[h*6+dh], s);
        p4[h] = __expf(s);
        lsum[h] += p4[h];
      }
      const unsigned int* vr = Vb + kp * 16;
      u32x4 va = *(const u32x4*)(vr);
      u32x4 vb2 = *(const u32x4*)(vr + 4);
      u32x4 vc = *(const u32x4*)(vr + 8);
      unsigned int vu[12] = {va[0],va[1],va[2],va[3], vb2[0],vb2[1],vb2[2],vb2[3], vc[0],vc[1],vc[2],vc[3]};
      float vvv[24];
      #pragma unroll
      for (int i = 0; i < 12; ++i) { vvv[2*i] = bflo(vu[i]); vvv[2*i+1] = bfhi(vu[i]); }
      #pragma unroll
      for (int h = 0; h < 4; ++h)
        #pragma unroll
        for (int dh = 0; dh < 6; ++dh)
          acc_o[h*6+dh] = fmaf(p4[h], vvv[h*6+dh], acc_o[h*6+dh]);
    }
    #pragma unroll
    for (int h = 0; h < 4; ++h) {
      const float inv = 1.0f / lsum[h];
      #pragma unroll
      for (int dh = 0; dh < 6; ++dh) acc_o[h*6+dh] *= inv;
    }
    // ---- O-proj + residual + LN1 ----
    const float* WO = wo + layer * 576;
    const float* BO = bo + layer * 24;
    float xo[24];
    #pragma unroll
    for (int j = 0; j < 24; ++j) {
      float s = BO[j];
      const float* wr = WO + j * 24;
      #pragma unroll
      for (int kd = 0; kd < 24; ++kd) s = fmaf(wr[kd], acc_o[kd], s);
      xo[j] = x[j] + s;
    }
    float mean = 0.f;
    #pragma unroll
    for (int j = 0; j < 24; ++j) mean += xo[j];
    mean *= (1.f / 24.f);
    float var = 0.f;
    #pragma unroll
    for (int j = 0; j < 24; ++j) { const float dd = xo[j] - mean; var = fmaf(dd, dd, var); }
    var *= (1.f / 24.f);
    const float rstd = rsqrtf(var + 1e-5f);
    const float* G1 = lg1 + layer * 24;
    const float* Bl1 = lb1 + layer * 24;
    float xn[24];
    #pragma unroll
    for (int j = 0; j < 24; ++j) xn[j] = (xo[j] - mean) * rstd * G1[j] + Bl1[j];
    // ---- FFN (relu) + residual ----
    const float* W1 = fw1 + layer * 96 * 24;
    const float* Bf1 = fb1 + layer * 96;
    const float* W2 = fw2 + layer * 24 * 96;
    const float* Bf2 = fb2 + layer * 24;
    float y[24];
    #pragma unroll
    for (int d = 0; d < 24; ++d) y[d] = xn[d] + Bf2[d];
    #pragma unroll 1
    for (int j = 0; j < 96; ++j) {
      float s = Bf1[j];
      const float* wr = W1 + j * 24;
      #pragma unroll
      for (int kd = 0; kd < 24; ++kd) s = fmaf(wr[kd], xn[kd], s);
      s = fmaxf(s, 0.f);
      #pragma unroll
      for (int d = 0; d < 24; ++d) y[d] = fmaf(s, W2[d * 96 + j], y[d]);
    }
    // ---- LN2 ----
    float mean2 = 0.f;
    #pragma unroll
    for (int j = 0; j < 24; ++j) mean2 += y[j];
    mean2 *= (1.f / 24.f);
    float var2 = 0.f;
    #pragma unroll
    for (int j = 0; j < 24; ++j) { const float dd = y[j] - mean2; var2 = fmaf(dd, dd, var2); }
    var2 *= (1.f / 24.f);
    const float rstd2 = rsqrtf(var2 + 1e-5f);
    const float* G2 = lg2 + layer * 24;
    const float* Bl2 = lb2 + layer * 24;
    #pragma unroll
    for (int j = 0; j < 24; ++j) xf[j] = (y[j] - mean2) * rstd2 * G2[j] + Bl2[j];
    if (layer == 0) {
      #pragma unroll
      for (int d = 0; d < 24; ++d) Xs[rowW * 28 + d] = xf[d];
    }
    __syncthreads();   // protect K/V overwrite next layer
  }
  if (storeOK) {
    float* op = out + (size_t)b * 1968 + t * 24;
    #pragma unroll
    for (int d4 = 0; d4 < 6; ++d4) {
      f32x4 v = { xf[4*d4], xf[4*d4+1], xf[4*d4+2], xf[4*d4+3] };
      *(f32x4*)(op + 4 * d4) = v;
    }
  }
}

// ---------------------------------------------------------------------------
extern "C" void kernel_launch(void* const* d_in, const int* in_sizes, int n_in,
                              void* d_out, int out_size, void* d_ws, size_t ws_size,
                              hipStream_t stream) {
  const float* gene    = (const float*)d_in[0];
  const float* protein = (const float*)d_in[1];
  const float* pathway = (const float*)d_in[2];
  const float* misc    = (const float*)d_in[3];
  const float* gw1 = (const float*)d_in[4];
  const float* gb1 = (const float*)d_in[5];
  const float* gg1 = (const float*)d_in[6];
  const float* gbb1= (const float*)d_in[7];
  const float* gw2 = (const float*)d_in[8];
  const float* gb2 = (const float*)d_in[9];
  const float* gg2 = (const float*)d_in[10];
  const float* gbb2= (const float*)d_in[11];
  const float* gw3 = (const float*)d_in[12];
  const float* gb3 = (const float*)d_in[13];
  const float* pw1 = (const float*)d_in[14];
  const float* pb1 = (const float*)d_in[15];
  const float* pg1 = (const float*)d_in[16];
  const float* pbb1= (const float*)d_in[17];
  const float* pw2 = (const float*)d_in[18];
  const float* pb2 = (const float*)d_in[19];
  const float* pg2 = (const float*)d_in[20];
  const float* pbb2= (const float*)d_in[21];
  const float* pw3 = (const float*)d_in[22];
  const float* pb3 = (const float*)d_in[23];
  const float* wqkv= (const float*)d_in[24];
  const float* bqkv= (const float*)d_in[25];
  const float* wo  = (const float*)d_in[26];
  const float* bo  = (const float*)d_in[27];
  const float* lg1 = (const float*)d_in[28];
  const float* lb1 = (const float*)d_in[29];
  const float* fw1 = (const float*)d_in[30];
  const float* fb1 = (const float*)d_in[31];
  const float* fw2 = (const float*)d_in[32];
  const float* fb2 = (const float*)d_in[33];
  const float* lg2 = (const float*)d_in[34];
  const float* lb2 = (const float*)d_in[35];

  const int B = in_sizes[0] / 5000;   // 8192

  float* bufA = (float*)d_ws;                          // [B,512]
  float* bufB = bufA + (size_t)B * 512;                // [B,512]
  float* logits_g = bufB + (size_t)B * 512;            // [B,82]
  float* logits_p = logits_g + (size_t)B * 82;         // [B,82]
  float* w_sum    = logits_p + (size_t)B * 82;         // [B,82]

  dim3 blk(256);
  // gene adapter: 5000 -> 512 -> 256 -> 82
  gemm_bias_kernel<<<dim3(B / 64, 4), blk, 0, stream>>>(gene, gw1, gb1, bufA, B, 512, 5000);
  ln_gelu_kernel<<<dim3(B), blk, 0, stream>>>(bufA, gg1, gbb1, bufB, 512);
  gemm_bias_kernel<<<dim3(B / 64, 2), blk, 0, stream>>>(bufB, gw2, gb2, bufA, B, 256, 512);
  ln_gelu_kernel<<<dim3(B), blk, 0, stream>>>(bufA, gg2, gbb2, bufB, 256);
  gemm_bias_kernel<<<dim3(B / 64, 1), blk, 0, stream>>>(bufB, gw3, gb3, logits_g, B, 82, 256);
  // protein adapter: 226 -> 512 -> 256 -> 82
  gemm_bias_kernel<<<dim3(B / 64, 4), blk, 0, stream>>>(protein, pw1, pb1, bufA, B, 512, 226);
  ln_gelu_kernel<<<dim3(B), blk, 0, stream>>>(bufA, pg1, pbb1, bufB, 512);
  gemm_bias_kernel<<<dim3(B / 64, 2), blk, 0, stream>>>(bufB, pw2, pb2, bufA, B, 256, 512);
  ln_gelu_kernel<<<dim3(B), blk, 0, stream>>>(bufA, pg2, pbb2, bufB, 256);
  gemm_bias_kernel<<<dim3(B / 64, 1), blk, 0, stream>>>(bufB, pw3, pb3, logits_p, B, 82, 256);
  // combine softmaxes
  softmax2_kernel<<<dim3((B + 3) / 4), blk, 0, stream>>>(logits_g, logits_p, w_sum, B);
  // fused 2-layer transformer encoder
  encoder_kernel<<<dim3((B + 2) / 3), blk, 0, stream>>>(w_sum, pathway, misc,
      wqkv, bqkv, wo, bo, lg1, lb1, fw1, fb1, fw2, fb2, lg2, lb2,
      (float*)d_out, B);
}

// Round 2
// 1157.990 us; speedup vs baseline: 1.3798x; 1.3798x over previous
//
#include <hip/hip_runtime.h>
#include <hip/hip_bf16.h>
#include <math.h>

typedef __attribute__((ext_vector_type(4))) float f32x4;
typedef __attribute__((ext_vector_type(8))) short s16x8;
typedef __attribute__((ext_vector_type(4))) short s16x4;
typedef __attribute__((ext_vector_type(4))) unsigned int u32x4;

static __device__ __forceinline__ unsigned short f2bf(float f) {
  unsigned int u = __builtin_bit_cast(unsigned int, f);
  u += 0x7FFFu + ((u >> 16) & 1u);           // RNE
  return (unsigned short)(u >> 16);
}
static __device__ __forceinline__ unsigned int pack2bf(float a, float b) {
  return (unsigned int)f2bf(a) | ((unsigned int)f2bf(b) << 16);
}
static __device__ __forceinline__ float bflo(unsigned int u) {
  return __builtin_bit_cast(float, u << 16);
}
// hi bf16 WITHOUT masking low bits: garbage mantissa bits add <=2^-8 relative
// error, same order as the bf16 rounding already applied. Saves the v_and.
static __device__ __forceinline__ float bfhiN(unsigned int u) {
  return __builtin_bit_cast(float, u);
}
static __device__ __forceinline__ float gelu_exact(float x) {
  return 0.5f * x * (1.0f + erff(x * 0.7071067811865475f));
}

// ---------------------------------------------------------------------------
// MFMA GEMM: C[M,N] = A[M,K] @ B[N,K]^T + bias   (fp32 in/out, bf16 MFMA)
// (unchanged from round 1 — verified correct)
// ---------------------------------------------------------------------------
#define GBM 64
#define GBN 128
#define GBK 64
#define GLDS 72

__global__ __launch_bounds__(256, 2)
void gemm_bias_kernel(const float* __restrict__ A, const float* __restrict__ Bw,
                      const float* __restrict__ bias, float* __restrict__ C,
                      int M, int N, int K) {
  __shared__ short As[GBM * GLDS];
  __shared__ short Bs[GBN * GLDS];
  const int tid = threadIdx.x;
  const int lane = tid & 63;
  const int wid = tid >> 6;
  const int wm = wid >> 1;
  const int wn = wid & 1;
  const int m0 = blockIdx.x * GBM;
  const int n0 = blockIdx.y * GBN;
  const int lr = lane & 15;
  const int lk = (lane >> 4) * 8;
  const bool kAligned = ((K & 3) == 0);

  f32x4 acc[2][4];
  #pragma unroll
  for (int i = 0; i < 2; ++i)
    #pragma unroll
    for (int j = 0; j < 4; ++j) acc[i][j] = (f32x4){0.f, 0.f, 0.f, 0.f};

  for (int k0 = 0; k0 < K; k0 += GBK) {
    __syncthreads();
    const bool fullK = kAligned && (k0 + GBK <= K);
    #pragma unroll
    for (int pass = 0; pass < 4; ++pass) {
      const int f = pass * 1024 + tid * 4;
      const int r = f >> 6, c = f & 63;
      f32x4 v = (f32x4){0.f, 0.f, 0.f, 0.f};
      const float* src = A + (size_t)(m0 + r) * K + (k0 + c);
      if (fullK) v = *(const f32x4*)src;
      else {
        #pragma unroll
        for (int i = 0; i < 4; ++i) if (k0 + c + i < K) v[i] = src[i];
      }
      s16x4 sv = { (short)f2bf(v[0]), (short)f2bf(v[1]), (short)f2bf(v[2]), (short)f2bf(v[3]) };
      *(s16x4*)&As[r * GLDS + c] = sv;
    }
    #pragma unroll
    for (int pass = 0; pass < 8; ++pass) {
      const int f = pass * 1024 + tid * 4;
      const int r = f >> 6, c = f & 63;
      f32x4 v = (f32x4){0.f, 0.f, 0.f, 0.f};
      if (n0 + r < N) {
        const float* src = Bw + (size_t)(n0 + r) * K + (k0 + c);
        if (fullK) v = *(const f32x4*)src;
        else {
          #pragma unroll
          for (int i = 0; i < 4; ++i) if (k0 + c + i < K) v[i] = src[i];
        }
      }
      s16x4 sv = { (short)f2bf(v[0]), (short)f2bf(v[1]), (short)f2bf(v[2]), (short)f2bf(v[3]) };
      *(s16x4*)&Bs[r * GLDS + c] = sv;
    }
    __syncthreads();
    #pragma unroll
    for (int kk = 0; kk < GBK; kk += 32) {
      s16x8 af[2], bfr[4];
      #pragma unroll
      for (int m = 0; m < 2; ++m)
        af[m] = *(const s16x8*)&As[(wm * 32 + m * 16 + lr) * GLDS + kk + lk];
      #pragma unroll
      for (int n = 0; n < 4; ++n)
        bfr[n] = *(const s16x8*)&Bs[(wn * 64 + n * 16 + lr) * GLDS + kk + lk];
      #pragma unroll
      for (int m = 0; m < 2; ++m)
        #pragma unroll
        for (int n = 0; n < 4; ++n)
          acc[m][n] = __builtin_amdgcn_mfma_f32_16x16x32_bf16(af[m], bfr[n], acc[m][n], 0, 0, 0);
    }
  }
  const int crow = (lane >> 4) * 4;
  #pragma unroll
  for (int m = 0; m < 2; ++m) {
    const int row = m0 + wm * 32 + m * 16 + crow;
    #pragma unroll
    for (int n = 0; n < 4; ++n) {
      const int col = n0 + wn * 64 + n * 16 + lr;
      if (col < N) {
        const float bv = bias[col];
        #pragma unroll
        for (int i = 0; i < 4; ++i)
          C[(size_t)(row + i) * N + col] = acc[m][n][i] + bv;
      }
    }
  }
}

// ---------------------------------------------------------------------------
// Row LayerNorm + exact GELU (unchanged)
// ---------------------------------------------------------------------------
__global__ __launch_bounds__(256)
void ln_gelu_kernel(const float* __restrict__ X, const float* __restrict__ g,
                    const float* __restrict__ bta, float* __restrict__ Y, int N) {
  const int row = blockIdx.x;
  const float* xr = X + (size_t)row * N;
  float* yr = Y + (size_t)row * N;
  const int tid = threadIdx.x;
  const float e0 = xr[tid];
  float e1 = 0.f;
  const bool two = (N > 256);
  if (two) e1 = xr[tid + 256];
  float s = e0 + e1;
  float ss = e0 * e0 + e1 * e1;
  #pragma unroll
  for (int off = 1; off < 64; off <<= 1) {
    s  += __shfl_xor(s, off);
    ss += __shfl_xor(ss, off);
  }
  __shared__ float red[8];
  const int w = tid >> 6;
  if ((tid & 63) == 0) { red[w] = s; red[4 + w] = ss; }
  __syncthreads();
  s  = red[0] + red[1] + red[2] + red[3];
  ss = red[4] + red[5] + red[6] + red[7];
  const float invN = 1.0f / (float)N;
  const float mean = s * invN;
  const float var = ss * invN - mean * mean;
  const float rstd = rsqrtf(var + 1e-5f);
  {
    const float z = (e0 - mean) * rstd * g[tid] + bta[tid];
    yr[tid] = gelu_exact(z);
  }
  if (two) {
    const float z = (e1 - mean) * rstd * g[tid + 256] + bta[tid + 256];
    yr[tid + 256] = gelu_exact(z);
  }
}

// ---------------------------------------------------------------------------
// w_sum = softmax(logits_g) + softmax(logits_p) (unchanged)
// ---------------------------------------------------------------------------
__global__ __launch_bounds__(256)
void softmax2_kernel(const float* __restrict__ la, const float* __restrict__ lp,
                     float* __restrict__ w, int B) {
  const int wid = threadIdx.x >> 6;
  const int lane = threadIdx.x & 63;
  const int row = blockIdx.x * 4 + wid;
  if (row >= B) return;
  const bool has2 = (lane < 18);
  const float* a = la + (size_t)row * 82;
  const float* p = lp + (size_t)row * 82;
  float a0 = a[lane], a1 = has2 ? a[64 + lane] : -1e30f;
  float m = fmaxf(a0, a1);
  #pragma unroll
  for (int off = 1; off < 64; off <<= 1) m = fmaxf(m, __shfl_xor(m, off));
  float ea0 = __expf(a0 - m);
  float ea1 = has2 ? __expf(a1 - m) : 0.f;
  float sa = ea0 + ea1;
  #pragma unroll
  for (int off = 1; off < 64; off <<= 1) sa += __shfl_xor(sa, off);
  float p0 = p[lane], p1 = has2 ? p[64 + lane] : -1e30f;
  float mp = fmaxf(p0, p1);
  #pragma unroll
  for (int off = 1; off < 64; off <<= 1) mp = fmaxf(mp, __shfl_xor(mp, off));
  float ep0 = __expf(p0 - mp);
  float ep1 = has2 ? __expf(p1 - mp) : 0.f;
  float sp = ep0 + ep1;
  #pragma unroll
  for (int off = 1; off < 64; off <<= 1) sp += __shfl_xor(sp, off);
  const float ia = 1.0f / sa, ip = 1.0f / sp;
  w[(size_t)row * 82 + lane] = ea0 * ia + ep0 * ip;
  if (has2) w[(size_t)row * 82 + 64 + lane] = ea1 * ia + ep1 * ip;
}

// ---------------------------------------------------------------------------
// Fused 2-layer post-norm TransformerEncoder, occupancy-optimized.
// thread = (seq,token), 3 seqs / 256-thread block.
// ALL LDS rows are packed bf16, 12 dwords (24 elems) per row:
//   Xs = residual stream (THREAD-PRIVATE: only own row is ever read ->
//        needs no barrier protection; it is a register spill buffer)
//   Ks/Vs = cross-thread K/V (barrier-protected as before)
// LDS total = 3 * 247 * 48 B = 34.7 KB -> 4 blocks/CU (16 waves, was 8).
// Attention loop hand-unrolled x2 with all 12 ds_read_b128 hoisted.
// ---------------------------------------------------------------------------
#define XROWS (3 * 82 + 1)

__global__ __launch_bounds__(256, 4)
void encoder_kernel(const float* __restrict__ w_sum,
                    const float* __restrict__ pathway, const float* __restrict__ misc,
                    const float* __restrict__ wqkv, const float* __restrict__ bqkv,
                    const float* __restrict__ wo, const float* __restrict__ bo,
                    const float* __restrict__ lg1, const float* __restrict__ lb1,
                    const float* __restrict__ fw1, const float* __restrict__ fb1,
                    const float* __restrict__ fw2, const float* __restrict__ fb2,
                    const float* __restrict__ lg2, const float* __restrict__ lb2,
                    float* __restrict__ out, int Btot) {
  __shared__ unsigned int Xs[XROWS * 12];
  __shared__ unsigned int Ks[XROWS * 12];
  __shared__ unsigned int Vs[XROWS * 12];

  const int tid = threadIdx.x;
  const bool active = (tid < 246);
  const int rowW = active ? tid : 246;          // 246 = dump row
  int ls = tid / 82; if (ls > 2) ls = 2;
  const int t = active ? (tid - ls * 82) : 0;
  const int b = blockIdx.x * 3 + ls;
  const bool storeOK = active && (b < Btot);
  const int bb = (b < Btot) ? b : (Btot - 1);

  // Phase 0: acts[t] = (gene_w+prot_w)[t] * all_tokens[t], packed bf16
  {
    const float* trow = (t < 50) ? (pathway + t * 24) : (misc + (t - 50) * 24);
    const float wv = w_sum[(size_t)bb * 82 + t];
    unsigned int px[12];
    #pragma unroll
    for (int i = 0; i < 6; ++i) {
      f32x4 v = *(const f32x4*)(trow + 4 * i);
      px[2*i]   = pack2bf(wv * v[0], wv * v[1]);
      px[2*i+1] = pack2bf(wv * v[2], wv * v[3]);
    }
    #pragma unroll
    for (int u = 0; u < 3; ++u)
      *(u32x4*)&Xs[rowW * 12 + 4*u] = (u32x4){px[4*u], px[4*u+1], px[4*u+2], px[4*u+3]};
  }
  // no barrier needed: Xs is thread-private, K/V not yet written

  float xf[24];
  #pragma unroll 1
  for (int layer = 0; layer < 2; ++layer) {
    const float* Wq = wqkv + layer * 72 * 24;
    const float* Bq = bqkv + layer * 72;

    // ---- Phase 1: QKV ----
    float x[24];
    {
      const unsigned int* xr = &Xs[rowW * 12];
      u32x4 xa = *(const u32x4*)(xr);
      u32x4 xbv = *(const u32x4*)(xr + 4);
      u32x4 xc = *(const u32x4*)(xr + 8);
      unsigned int xu[12] = {xa[0],xa[1],xa[2],xa[3], xbv[0],xbv[1],xbv[2],xbv[3], xc[0],xc[1],xc[2],xc[3]};
      #pragma unroll
      for (int i = 0; i < 12; ++i) { x[2*i] = bflo(xu[i]); x[2*i+1] = bfhiN(xu[i]); }
    }
    float q[24];
    #pragma unroll
    for (int j = 0; j < 24; ++j) {
      float s = Bq[j];
      const float* wr = Wq + j * 24;
      #pragma unroll
      for (int kd = 0; kd < 24; ++kd) s = fmaf(wr[kd], x[kd], s);
      q[j] = s * 0.40824829046386302f;   // 1/sqrt(6) folded into q
    }
    {
      unsigned int pk[12];
      #pragma unroll
      for (int j2 = 0; j2 < 12; ++j2) {          // K rows (24..47)
        float s0 = Bq[24 + 2*j2], s1 = Bq[25 + 2*j2];
        const float* w0 = Wq + (24 + 2*j2) * 24;
        #pragma unroll
        for (int kd = 0; kd < 24; ++kd) {
          s0 = fmaf(w0[kd], x[kd], s0);
          s1 = fmaf(w0[24 + kd], x[kd], s1);
        }
        pk[j2] = pack2bf(s0, s1);
      }
      #pragma unroll
      for (int u = 0; u < 3; ++u)
        *(u32x4*)&Ks[rowW * 12 + 4*u] = (u32x4){pk[4*u], pk[4*u+1], pk[4*u+2], pk[4*u+3]};
      #pragma unroll
      for (int j2 = 0; j2 < 12; ++j2) {          // V rows (48..71)
        float s0 = Bq[48 + 2*j2], s1 = Bq[49 + 2*j2];
        const float* w0 = Wq + (48 + 2*j2) * 24;
        #pragma unroll
        for (int kd = 0; kd < 24; ++kd) {
          s0 = fmaf(w0[kd], x[kd], s0);
          s1 = fmaf(w0[24 + kd], x[kd], s1);
        }
        pk[j2] = pack2bf(s0, s1);
      }
      #pragma unroll
      for (int u = 0; u < 3; ++u)
        *(u32x4*)&Vs[rowW * 12 + 4*u] = (u32x4){pk[4*u], pk[4*u+1], pk[4*u+2], pk[4*u+3]};
    }
    __syncthreads();

    // ---- Phase 2: attention, 2 keys per iteration ----
    float acc_o[24];
    float lsum[4] = {0.f, 0.f, 0.f, 0.f};
    #pragma unroll
    for (int d = 0; d < 24; ++d) acc_o[d] = 0.f;
    const unsigned int* Kb = &Ks[ls * 82 * 12];
    const unsigned int* Vb = &Vs[ls * 82 * 12];
    #pragma unroll 1
    for (int kp = 0; kp < 82; kp += 2) {
      const unsigned int* kr = Kb + kp * 12;
      u32x4 k0a = *(const u32x4*)(kr);
      u32x4 k0b = *(const u32x4*)(kr + 4);
      u32x4 k0c = *(const u32x4*)(kr + 8);
      u32x4 k1a = *(const u32x4*)(kr + 12);
      u32x4 k1b = *(const u32x4*)(kr + 16);
      u32x4 k1c = *(const u32x4*)(kr + 20);
      const unsigned int* vr = Vb + kp * 12;
      u32x4 v0a = *(const u32x4*)(vr);
      u32x4 v0b = *(const u32x4*)(vr + 4);
      u32x4 v0c = *(const u32x4*)(vr + 8);
      u32x4 v1a = *(const u32x4*)(vr + 12);
      u32x4 v1b = *(const u32x4*)(vr + 16);
      u32x4 v1c = *(const u32x4*)(vr + 20);
      unsigned int k0u[12] = {k0a[0],k0a[1],k0a[2],k0a[3], k0b[0],k0b[1],k0b[2],k0b[3], k0c[0],k0c[1],k0c[2],k0c[3]};
      unsigned int k1u[12] = {k1a[0],k1a[1],k1a[2],k1a[3], k1b[0],k1b[1],k1b[2],k1b[3], k1c[0],k1c[1],k1c[2],k1c[3]};
      unsigned int v0u[12] = {v0a[0],v0a[1],v0a[2],v0a[3], v0b[0],v0b[1],v0b[2],v0b[3], v0c[0],v0c[1],v0c[2],v0c[3]};
      unsigned int v1u[12] = {v1a[0],v1a[1],v1a[2],v1a[3], v1b[0],v1b[1],v1b[2],v1b[3], v1c[0],v1c[1],v1c[2],v1c[3]};
      #pragma unroll
      for (int h = 0; h < 4; ++h) {
        const int p0i = 3 * h, e0 = 6 * h;
        float s0 = q[e0] * bflo(k0u[p0i]);
        s0 = fmaf(q[e0+1], bfhiN(k0u[p0i]), s0);
        s0 = fmaf(q[e0+2], bflo(k0u[p0i+1]), s0);
        s0 = fmaf(q[e0+3], bfhiN(k0u[p0i+1]), s0);
        s0 = fmaf(q[e0+4], bflo(k0u[p0i+2]), s0);
        s0 = fmaf(q[e0+5], bfhiN(k0u[p0i+2]), s0);
        float s1 = q[e0] * bflo(k1u[p0i]);
        s1 = fmaf(q[e0+1], bfhiN(k1u[p0i]), s1);
        s1 = fmaf(q[e0+2], bflo(k1u[p0i+1]), s1);
        s1 = fmaf(q[e0+3], bfhiN(k1u[p0i+1]), s1);
        s1 = fmaf(q[e0+4], bflo(k1u[p0i+2]), s1);
        s1 = fmaf(q[e0+5], bfhiN(k1u[p0i+2]), s1);
        const float p0 = __expf(s0);
        const float p1 = __expf(s1);
        lsum[h] += p0 + p1;
        #pragma unroll
        for (int i = 0; i < 3; ++i) {
          const int pi = p0i + i, ee = e0 + 2 * i;
          acc_o[ee]   = fmaf(p1, bflo(v1u[pi]),  fmaf(p0, bflo(v0u[pi]),  acc_o[ee]));
          acc_o[ee+1] = fmaf(p1, bfhiN(v1u[pi]), fmaf(p0, bfhiN(v0u[pi]), acc_o[ee+1]));
        }
      }
    }
    #pragma unroll
    for (int h = 0; h < 4; ++h) {
      const float inv = 1.0f / lsum[h];
      #pragma unroll
      for (int dh = 0; dh < 6; ++dh) acc_o[h*6+dh] *= inv;
    }
    // ---- O-proj + residual (re-read own x row) + LN1 ----
    {
      const unsigned int* xr = &Xs[rowW * 12];
      u32x4 xa = *(const u32x4*)(xr);
      u32x4 xbv = *(const u32x4*)(xr + 4);
      u32x4 xc = *(const u32x4*)(xr + 8);
      unsigned int xu[12] = {xa[0],xa[1],xa[2],xa[3], xbv[0],xbv[1],xbv[2],xbv[3], xc[0],xc[1],xc[2],xc[3]};
      #pragma unroll
      for (int i = 0; i < 12; ++i) { x[2*i] = bflo(xu[i]); x[2*i+1] = bfhiN(xu[i]); }
    }
    const float* WO = wo + layer * 576;
    const float* BO = bo + layer * 24;
    float xo[24];
    #pragma unroll
    for (int j = 0; j < 24; ++j) {
      float s = BO[j];
      const float* wr = WO + j * 24;
      #pragma unroll
      for (int kd = 0; kd < 24; ++kd) s = fmaf(wr[kd], acc_o[kd], s);
      xo[j] = x[j] + s;
    }
    float mean = 0.f;
    #pragma unroll
    for (int j = 0; j < 24; ++j) mean += xo[j];
    mean *= (1.f / 24.f);
    float var = 0.f;
    #pragma unroll
    for (int j = 0; j < 24; ++j) { const float dd = xo[j] - mean; var = fmaf(dd, dd, var); }
    var *= (1.f / 24.f);
    const float rstd = rsqrtf(var + 1e-5f);
    const float* G1 = lg1 + layer * 24;
    const float* Bl1 = lb1 + layer * 24;
    float xn[24];
    #pragma unroll
    for (int j = 0; j < 24; ++j) xn[j] = (xo[j] - mean) * rstd * G1[j] + Bl1[j];
    // ---- FFN (relu) + residual ----
    const float* W1 = fw1 + layer * 96 * 24;
    const float* Bf1 = fb1 + layer * 96;
    const float* W2 = fw2 + layer * 24 * 96;
    const float* Bf2 = fb2 + layer * 24;
    float y[24];
    #pragma unroll
    for (int d = 0; d < 24; ++d) y[d] = xn[d] + Bf2[d];
    #pragma unroll 1
    for (int j = 0; j < 96; j += 2) {
      float sa = Bf1[j], sb = Bf1[j + 1];
      const float* wr = W1 + j * 24;
      #pragma unroll
      for (int kd = 0; kd < 24; ++kd) {
        sa = fmaf(wr[kd], xn[kd], sa);
        sb = fmaf(wr[24 + kd], xn[kd], sb);
      }
      sa = fmaxf(sa, 0.f);
      sb = fmaxf(sb, 0.f);
      #pragma unroll
      for (int d = 0; d < 24; ++d)
        y[d] = fmaf(sb, W2[d * 96 + j + 1], fmaf(sa, W2[d * 96 + j], y[d]));
    }
    // ---- LN2 ----
    float mean2 = 0.f;
    #pragma unroll
    for (int j = 0; j < 24; ++j) mean2 += y[j];
    mean2 *= (1.f / 24.f);
    float var2 = 0.f;
    #pragma unroll
    for (int j = 0; j < 24; ++j) { const float dd = y[j] - mean2; var2 = fmaf(dd, dd, var2); }
    var2 *= (1.f / 24.f);
    const float rstd2 = rsqrtf(var2 + 1e-5f);
    const float* G2 = lg2 + layer * 24;
    const float* Bl2 = lb2 + layer * 24;
    #pragma unroll
    for (int j = 0; j < 24; ++j) xf[j] = (y[j] - mean2) * rstd2 * G2[j] + Bl2[j];
    if (layer == 0) {
      unsigned int px[12];
      #pragma unroll
      for (int i = 0; i < 12; ++i) px[i] = pack2bf(xf[2*i], xf[2*i+1]);
      #pragma unroll
      for (int u = 0; u < 3; ++u)
        *(u32x4*)&Xs[rowW * 12 + 4*u] = (u32x4){px[4*u], px[4*u+1], px[4*u+2], px[4*u+3]};
    }
    __syncthreads();   // all attention reads done before next layer's K/V writes
  }
  if (storeOK) {
    float* op = out + (size_t)b * 1968 + t * 24;
    #pragma unroll
    for (int d4 = 0; d4 < 6; ++d4) {
      f32x4 v = { xf[4*d4], xf[4*d4+1], xf[4*d4+2], xf[4*d4+3] };
      *(f32x4*)(op + 4 * d4) = v;
    }
  }
}

// ---------------------------------------------------------------------------
extern "C" void kernel_launch(void* const* d_in, const int* in_sizes, int n_in,
                              void* d_out, int out_size, void* d_ws, size_t ws_size,
                              hipStream_t stream) {
  const float* gene    = (const float*)d_in[0];
  const float* protein = (const float*)d_in[1];
  const float* pathway = (const float*)d_in[2];
  const float* misc    = (const float*)d_in[3];
  const float* gw1 = (const float*)d_in[4];
  const float* gb1 = (const float*)d_in[5];
  const float* gg1 = (const float*)d_in[6];
  const float* gbb1= (const float*)d_in[7];
  const float* gw2 = (const float*)d_in[8];
  const float* gb2 = (const float*)d_in[9];
  const float* gg2 = (const float*)d_in[10];
  const float* gbb2= (const float*)d_in[11];
  const float* gw3 = (const float*)d_in[12];
  const float* gb3 = (const float*)d_in[13];
  const float* pw1 = (const float*)d_in[14];
  const float* pb1 = (const float*)d_in[15];
  const float* pg1 = (const float*)d_in[16];
  const float* pbb1= (const float*)d_in[17];
  const float* pw2 = (const float*)d_in[18];
  const float* pb2 = (const float*)d_in[19];
  const float* pg2 = (const float*)d_in[20];
  const float* pbb2= (const float*)d_in[21];
  const float* pw3 = (const float*)d_in[22];
  const float* pb3 = (const float*)d_in[23];
  const float* wqkv= (const float*)d_in[24];
  const float* bqkv= (const float*)d_in[25];
  const float* wo  = (const float*)d_in[26];
  const float* bo  = (const float*)d_in[27];
  const float* lg1 = (const float*)d_in[28];
  const float* lb1 = (const float*)d_in[29];
  const float* fw1 = (const float*)d_in[30];
  const float* fb1 = (const float*)d_in[31];
  const float* fw2 = (const float*)d_in[32];
  const float* fb2 = (const float*)d_in[33];
  const float* lg2 = (const float*)d_in[34];
  const float* lb2 = (const float*)d_in[35];

  const int B = in_sizes[0] / 5000;   // 8192

  float* bufA = (float*)d_ws;                          // [B,512]
  float* bufB = bufA + (size_t)B * 512;                // [B,512]
  float* logits_g = bufB + (size_t)B * 512;            // [B,82]
  float* logits_p = logits_g + (size_t)B * 82;         // [B,82]
  float* w_sum    = logits_p + (size_t)B * 82;         // [B,82]

  dim3 blk(256);
  // gene adapter: 5000 -> 512 -> 256 -> 82
  gemm_bias_kernel<<<dim3(B / 64, 4), blk, 0, stream>>>(gene, gw1, gb1, bufA, B, 512, 5000);
  ln_gelu_kernel<<<dim3(B), blk, 0, stream>>>(bufA, gg1, gbb1, bufB, 512);
  gemm_bias_kernel<<<dim3(B / 64, 2), blk, 0, stream>>>(bufB, gw2, gb2, bufA, B, 256, 512);
  ln_gelu_kernel<<<dim3(B), blk, 0, stream>>>(bufA, gg2, gbb2, bufB, 256);
  gemm_bias_kernel<<<dim3(B / 64, 1), blk, 0, stream>>>(bufB, gw3, gb3, logits_g, B, 82, 256);
  // protein adapter: 226 -> 512 -> 256 -> 82
  gemm_bias_kernel<<<dim3(B / 64, 4), blk, 0, stream>>>(protein, pw1, pb1, bufA, B, 512, 226);
  ln_gelu_kernel<<<dim3(B), blk, 0, stream>>>(bufA, pg1, pbb1, bufB, 512);
  gemm_bias_kernel<<<dim3(B / 64, 2), blk, 0, stream>>>(bufB, pw2, pb2, bufA, B, 256, 512);
  ln_gelu_kernel<<<dim3(B), blk, 0, stream>>>(bufA, pg2, pbb2, bufB, 256);
  gemm_bias_kernel<<<dim3(B / 64, 1), blk, 0, stream>>>(bufB, pw3, pb3, logits_p, B, 82, 256);
  // combine softmaxes
  softmax2_kernel<<<dim3((B + 3) / 4), blk, 0, stream>>>(logits_g, logits_p, w_sum, B);
  // fused 2-layer transformer encoder
  encoder_kernel<<<dim3((B + 2) / 3), blk, 0, stream>>>(w_sum, pathway, misc,
      wqkv, bqkv, wo, bo, lg1, lb1, fw1, fb1, fw2, fb2, lg2, lb2,
      (float*)d_out, B);
}

// Round 4
// 889.713 us; speedup vs baseline: 1.7958x; 1.3015x over previous
//
#include <hip/hip_runtime.h>
#include <hip/hip_bf16.h>
#include <math.h>

typedef __attribute__((ext_vector_type(4))) float f32x4;
typedef __attribute__((ext_vector_type(8))) short s16x8;
typedef __attribute__((ext_vector_type(4))) short s16x4;
typedef __attribute__((ext_vector_type(4))) unsigned int u32x4;
typedef _Float16 h2 __attribute__((ext_vector_type(2)));

static __device__ __forceinline__ unsigned short f2bf(float f) {
  unsigned int u = __builtin_bit_cast(unsigned int, f);
  u += 0x7FFFu + ((u >> 16) & 1u);           // RNE
  return (unsigned short)(u >> 16);
}
static __device__ __forceinline__ float gelu_exact(float x) {
  return 0.5f * x * (1.0f + erff(x * 0.7071067811865475f));
}
static __device__ __forceinline__ h2 pkh2(float a, float b) {
#if __has_builtin(__builtin_amdgcn_cvt_pkrtz)
  return __builtin_bit_cast(h2, __builtin_amdgcn_cvt_pkrtz(a, b));
#else
  h2 r; r[0] = (_Float16)a; r[1] = (_Float16)b; return r;
#endif
}
// dot2: a (VGPR h2 pair) . b (packed-f16 dword, usually SGPR) + c, f32 acc
static __device__ __forceinline__ float dot2u(h2 a, unsigned int b, float c) {
  h2 bh = __builtin_bit_cast(h2, b);
#if __has_builtin(__builtin_amdgcn_fdot2)
  return __builtin_amdgcn_fdot2(a, bh, c, false);
#else
  return fmaf((float)a[0], (float)bh[0], fmaf((float)a[1], (float)bh[1], c));
#endif
}
static __device__ __forceinline__ float exp2fast(float x) {
#if __has_builtin(__builtin_amdgcn_exp2f)
  return __builtin_amdgcn_exp2f(x);
#else
  return exp2f(x);
#endif
}

// ---------------------------------------------------------------------------
// MFMA GEMM: C[M,N] = A[M,K] @ B[N,K]^T + bias  (unchanged, verified)
// ---------------------------------------------------------------------------
#define GBM 64
#define GBN 128
#define GBK 64
#define GLDS 72

__global__ __launch_bounds__(256, 2)
void gemm_bias_kernel(const float* __restrict__ A, const float* __restrict__ Bw,
                      const float* __restrict__ bias, float* __restrict__ C,
                      int M, int N, int K) {
  __shared__ short As[GBM * GLDS];
  __shared__ short Bs[GBN * GLDS];
  const int tid = threadIdx.x;
  const int lane = tid & 63;
  const int wid = tid >> 6;
  const int wm = wid >> 1;
  const int wn = wid & 1;
  const int m0 = blockIdx.x * GBM;
  const int n0 = blockIdx.y * GBN;
  const int lr = lane & 15;
  const int lk = (lane >> 4) * 8;
  const bool kAligned = ((K & 3) == 0);

  f32x4 acc[2][4];
  #pragma unroll
  for (int i = 0; i < 2; ++i)
    #pragma unroll
    for (int j = 0; j < 4; ++j) acc[i][j] = (f32x4){0.f, 0.f, 0.f, 0.f};

  for (int k0 = 0; k0 < K; k0 += GBK) {
    __syncthreads();
    const bool fullK = kAligned && (k0 + GBK <= K);
    #pragma unroll
    for (int pass = 0; pass < 4; ++pass) {
      const int f = pass * 1024 + tid * 4;
      const int r = f >> 6, c = f & 63;
      f32x4 v = (f32x4){0.f, 0.f, 0.f, 0.f};
      const float* src = A + (size_t)(m0 + r) * K + (k0 + c);
      if (fullK) v = *(const f32x4*)src;
      else {
        #pragma unroll
        for (int i = 0; i < 4; ++i) if (k0 + c + i < K) v[i] = src[i];
      }
      s16x4 sv = { (short)f2bf(v[0]), (short)f2bf(v[1]), (short)f2bf(v[2]), (short)f2bf(v[3]) };
      *(s16x4*)&As[r * GLDS + c] = sv;
    }
    #pragma unroll
    for (int pass = 0; pass < 8; ++pass) {
      const int f = pass * 1024 + tid * 4;
      const int r = f >> 6, c = f & 63;
      f32x4 v = (f32x4){0.f, 0.f, 0.f, 0.f};
      if (n0 + r < N) {
        const float* src = Bw + (size_t)(n0 + r) * K + (k0 + c);
        if (fullK) v = *(const f32x4*)src;
        else {
          #pragma unroll
          for (int i = 0; i < 4; ++i) if (k0 + c + i < K) v[i] = src[i];
        }
      }
      s16x4 sv = { (short)f2bf(v[0]), (short)f2bf(v[1]), (short)f2bf(v[2]), (short)f2bf(v[3]) };
      *(s16x4*)&Bs[r * GLDS + c] = sv;
    }
    __syncthreads();
    #pragma unroll
    for (int kk = 0; kk < GBK; kk += 32) {
      s16x8 af[2], bfr[4];
      #pragma unroll
      for (int m = 0; m < 2; ++m)
        af[m] = *(const s16x8*)&As[(wm * 32 + m * 16 + lr) * GLDS + kk + lk];
      #pragma unroll
      for (int n = 0; n < 4; ++n)
        bfr[n] = *(const s16x8*)&Bs[(wn * 64 + n * 16 + lr) * GLDS + kk + lk];
      #pragma unroll
      for (int m = 0; m < 2; ++m)
        #pragma unroll
        for (int n = 0; n < 4; ++n)
          acc[m][n] = __builtin_amdgcn_mfma_f32_16x16x32_bf16(af[m], bfr[n], acc[m][n], 0, 0, 0);
    }
  }
  const int crow = (lane >> 4) * 4;
  #pragma unroll
  for (int m = 0; m < 2; ++m) {
    const int row = m0 + wm * 32 + m * 16 + crow;
    #pragma unroll
    for (int n = 0; n < 4; ++n) {
      const int col = n0 + wn * 64 + n * 16 + lr;
      if (col < N) {
        const float bv = bias[col];
        #pragma unroll
        for (int i = 0; i < 4; ++i)
          C[(size_t)(row + i) * N + col] = acc[m][n][i] + bv;
      }
    }
  }
}

// ---------------------------------------------------------------------------
// Row LayerNorm + exact GELU (unchanged)
// ---------------------------------------------------------------------------
__global__ __launch_bounds__(256)
void ln_gelu_kernel(const float* __restrict__ X, const float* __restrict__ g,
                    const float* __restrict__ bta, float* __restrict__ Y, int N) {
  const int row = blockIdx.x;
  const float* xr = X + (size_t)row * N;
  float* yr = Y + (size_t)row * N;
  const int tid = threadIdx.x;
  const float e0 = xr[tid];
  float e1 = 0.f;
  const bool two = (N > 256);
  if (two) e1 = xr[tid + 256];
  float s = e0 + e1;
  float ss = e0 * e0 + e1 * e1;
  #pragma unroll
  for (int off = 1; off < 64; off <<= 1) {
    s  += __shfl_xor(s, off);
    ss += __shfl_xor(ss, off);
  }
  __shared__ float red[8];
  const int w = tid >> 6;
  if ((tid & 63) == 0) { red[w] = s; red[4 + w] = ss; }
  __syncthreads();
  s  = red[0] + red[1] + red[2] + red[3];
  ss = red[4] + red[5] + red[6] + red[7];
  const float invN = 1.0f / (float)N;
  const float mean = s * invN;
  const float var = ss * invN - mean * mean;
  const float rstd = rsqrtf(var + 1e-5f);
  {
    const float z = (e0 - mean) * rstd * g[tid] + bta[tid];
    yr[tid] = gelu_exact(z);
  }
  if (two) {
    const float z = (e1 - mean) * rstd * g[tid + 256] + bta[tid + 256];
    yr[tid + 256] = gelu_exact(z);
  }
}

// ---------------------------------------------------------------------------
// w_sum = softmax(logits_g) + softmax(logits_p) (unchanged)
// ---------------------------------------------------------------------------
__global__ __launch_bounds__(256)
void softmax2_kernel(const float* __restrict__ la, const float* __restrict__ lp,
                     float* __restrict__ w, int B) {
  const int wid = threadIdx.x >> 6;
  const int lane = threadIdx.x & 63;
  const int row = blockIdx.x * 4 + wid;
  if (row >= B) return;
  const bool has2 = (lane < 18);
  const float* a = la + (size_t)row * 82;
  const float* p = lp + (size_t)row * 82;
  float a0 = a[lane], a1 = has2 ? a[64 + lane] : -1e30f;
  float m = fmaxf(a0, a1);
  #pragma unroll
  for (int off = 1; off < 64; off <<= 1) m = fmaxf(m, __shfl_xor(m, off));
  float ea0 = __expf(a0 - m);
  float ea1 = has2 ? __expf(a1 - m) : 0.f;
  float sa = ea0 + ea1;
  #pragma unroll
  for (int off = 1; off < 64; off <<= 1) sa += __shfl_xor(sa, off);
  float p0 = p[lane], p1 = has2 ? p[64 + lane] : -1e30f;
  float mp = fmaxf(p0, p1);
  #pragma unroll
  for (int off = 1; off < 64; off <<= 1) mp = fmaxf(mp, __shfl_xor(mp, off));
  float ep0 = __expf(p0 - mp);
  float ep1 = has2 ? __expf(p1 - mp) : 0.f;
  float sp = ep0 + ep1;
  #pragma unroll
  for (int off = 1; off < 64; off <<= 1) sp += __shfl_xor(sp, off);
  const float ia = 1.0f / sa, ip = 1.0f / sp;
  w[(size_t)row * 82 + lane] = ea0 * ia + ep0 * ip;
  if (has2) w[(size_t)row * 82 + 64 + lane] = ea1 * ia + ep1 * ip;
}

// ---------------------------------------------------------------------------
// Weight pre-pack: f32 -> packed f16-pair dwords.
// Layout in dst (dwords):
//   [0,1728)    wqkv  [2][72][12]  pairs along k
//   [1728,2304) wo    [2][24][12]
//   [2304,4608) fw1   [2][96][12]
//   [4608,6912) fw2T  [2][48][24]  TRANSPOSED: dword(jp,d) = (w2[d][2jp], w2[d][2jp+1])
// ---------------------------------------------------------------------------
__global__ __launch_bounds__(256)
void pack_weights_kernel(const float* __restrict__ wqkv, const float* __restrict__ wo,
                         const float* __restrict__ fw1, const float* __restrict__ fw2,
                         unsigned int* __restrict__ dst) {
  const int i = blockIdx.x * 256 + threadIdx.x;
  if (i >= 6912) return;
  float a, b;
  if (i < 1728)      { a = wqkv[2 * i];            b = wqkv[2 * i + 1]; }
  else if (i < 2304) { int j = i - 1728; a = wo[2 * j];  b = wo[2 * j + 1]; }
  else if (i < 4608) { int j = i - 2304; a = fw1[2 * j]; b = fw1[2 * j + 1]; }
  else {
    int j = i - 4608; int layer = j / 1152; int r = j % 1152;
    int jp = r / 24; int d = r % 24;
    const float* s = fw2 + layer * 2304 + d * 96 + 2 * jp;
    a = s[0]; b = s[1];
  }
  unsigned short lo = __builtin_bit_cast(unsigned short, (_Float16)a);
  unsigned short hi = __builtin_bit_cast(unsigned short, (_Float16)b);
  dst[i] = (unsigned int)lo | ((unsigned int)hi << 16);
}

// ---------------------------------------------------------------------------
// Fused 2-layer post-norm TransformerEncoder, v_dot2_f32_f16 edition.
// thread = (seq,token), 3 seqs / block. Residual x[24] lives in VGPRs.
// LDS: Ks f16 row-major [247][12] dwords; Vs pair-transposed f16
//   [124 rows][28 dwords] (row = (seq,keypair), dword j = (v_2k[j], v_2k+1[j])).
// Weights read as packed-f16 dwords (uniform -> s_load), math via dot2.
// exp2 with log2e folded into q scale.
// ---------------------------------------------------------------------------
#define VSTRIDE 28

__global__ __launch_bounds__(256, 4)
void encoder_kernel(const float* __restrict__ w_sum,
                    const float* __restrict__ pathway, const float* __restrict__ misc,
                    const unsigned int* __restrict__ whb,
                    const float* __restrict__ bqkv, const float* __restrict__ bo,
                    const float* __restrict__ lg1, const float* __restrict__ lb1,
                    const float* __restrict__ fb1, const float* __restrict__ fb2,
                    const float* __restrict__ lg2, const float* __restrict__ lb2,
                    float* __restrict__ out, int Btot) {
  __shared__ unsigned int Ks[247 * 12];
  __shared__ unsigned int Vs[124 * VSTRIDE];

  const int tid = threadIdx.x;
  const bool active = (tid < 246);
  const int rowW = active ? tid : 246;            // K dump row
  int ls = tid / 82; if (ls > 2) ls = 2;
  const int t = active ? (tid - ls * 82) : 0;
  const int vrow = active ? (ls * 41 + (t >> 1)) : 123;   // V dump row
  const int b = blockIdx.x * 3 + ls;
  const bool storeOK = active && (b < Btot);
  const int bb = (b < Btot) ? b : (Btot - 1);

  // Phase 0: x = (gene_w+prot_w)[t] * all_tokens[t]  (stays in VGPRs)
  float x[24];
  {
    const float* trow = (t < 50) ? (pathway + t * 24) : (misc + (t - 50) * 24);
    const float wv = w_sum[(size_t)bb * 82 + t];
    #pragma unroll
    for (int i = 0; i < 6; ++i) {
      f32x4 v = *(const f32x4*)(trow + 4 * i);
      x[4*i+0] = wv * v[0]; x[4*i+1] = wv * v[1];
      x[4*i+2] = wv * v[2]; x[4*i+3] = wv * v[3];
    }
  }

  const float QS = 0.5889777913f;   // 1/sqrt(6) * log2(e)
  float xf[24];
  #pragma unroll 1
  for (int layer = 0; layer < 2; ++layer) {
    const unsigned int* Wqh = whb + layer * 864;           // [72][12]
    const unsigned int* Woh = whb + 1728 + layer * 288;    // [24][12]
    const unsigned int* F1h = whb + 2304 + layer * 1152;   // [96][12]
    const unsigned int* F2t = whb + 4608 + layer * 1152;   // [48][24]
    const float* Bq = bqkv + layer * 72;

    // ---- Phase 1: QKV via dot2 ----
    h2 xh[12];
    #pragma unroll
    for (int i = 0; i < 12; ++i) xh[i] = pkh2(x[2*i], x[2*i+1]);
    h2 qh[12];
    #pragma unroll
    for (int j2 = 0; j2 < 12; ++j2) {
      float s0 = Bq[2*j2], s1 = Bq[2*j2+1];
      const unsigned int* w0 = Wqh + (2*j2) * 12;
      #pragma unroll
      for (int kd = 0; kd < 12; ++kd) {
        s0 = dot2u(xh[kd], w0[kd], s0);
        s1 = dot2u(xh[kd], w0[12 + kd], s1);
      }
      qh[j2] = pkh2(s0 * QS, s1 * QS);
    }
    {
      unsigned int kpk[12];
      #pragma unroll
      for (int j2 = 0; j2 < 12; ++j2) {          // K rows 24..47
        float s0 = Bq[24 + 2*j2], s1 = Bq[25 + 2*j2];
        const unsigned int* w0 = Wqh + (24 + 2*j2) * 12;
        #pragma unroll
        for (int kd = 0; kd < 12; ++kd) {
          s0 = dot2u(xh[kd], w0[kd], s0);
          s1 = dot2u(xh[kd], w0[12 + kd], s1);
        }
        kpk[j2] = __builtin_bit_cast(unsigned int, pkh2(s0, s1));
      }
      #pragma unroll
      for (int u = 0; u < 3; ++u)
        *(u32x4*)&Ks[rowW * 12 + 4*u] = (u32x4){kpk[4*u], kpk[4*u+1], kpk[4*u+2], kpk[4*u+3]};
      float vv[24];
      #pragma unroll
      for (int j2 = 0; j2 < 12; ++j2) {          // V rows 48..71
        float s0 = Bq[48 + 2*j2], s1 = Bq[49 + 2*j2];
        const unsigned int* w0 = Wqh + (48 + 2*j2) * 12;
        #pragma unroll
        for (int kd = 0; kd < 12; ++kd) {
          s0 = dot2u(xh[kd], w0[kd], s0);
          s1 = dot2u(xh[kd], w0[12 + kd], s1);
        }
        vv[2*j2] = s0; vv[2*j2+1] = s1;
      }
      // pair-transposed V: thread t writes half (t&1) of dword (vrow, j)
      _Float16* vh = (_Float16*)Vs;
      const int vbase = vrow * (2 * VSTRIDE) + (t & 1);
      #pragma unroll
      for (int j = 0; j < 24; ++j) vh[vbase + 2*j] = (_Float16)vv[j];
    }
    __syncthreads();

    // ---- Phase 2: attention, one key-PAIR per iteration ----
    float acc_o[24];
    float lsum[4] = {0.f, 0.f, 0.f, 0.f};
    #pragma unroll
    for (int d = 0; d < 24; ++d) acc_o[d] = 0.f;
    const unsigned int* Kb = Ks + ls * 82 * 12;
    const unsigned int* Vb = Vs + ls * 41 * VSTRIDE;
    #pragma unroll 1
    for (int kp = 0; kp < 41; ++kp) {
      const unsigned int* kr = Kb + kp * 24;
      u32x4 ka = *(const u32x4*)(kr);
      u32x4 kbv = *(const u32x4*)(kr + 4);
      u32x4 kc = *(const u32x4*)(kr + 8);
      u32x4 kd_ = *(const u32x4*)(kr + 12);
      u32x4 ke = *(const u32x4*)(kr + 16);
      u32x4 kf = *(const u32x4*)(kr + 20);
      unsigned int k0u[12] = {ka[0],ka[1],ka[2],ka[3], kbv[0],kbv[1],kbv[2],kbv[3], kc[0],kc[1],kc[2],kc[3]};
      unsigned int k1u[12] = {kd_[0],kd_[1],kd_[2],kd_[3], ke[0],ke[1],ke[2],ke[3], kf[0],kf[1],kf[2],kf[3]};
      float p0[4], p1[4];
      #pragma unroll
      for (int h = 0; h < 4; ++h) {
        float s0 = dot2u(qh[3*h], k0u[3*h], 0.f);
        s0 = dot2u(qh[3*h+1], k0u[3*h+1], s0);
        s0 = dot2u(qh[3*h+2], k0u[3*h+2], s0);
        float s1 = dot2u(qh[3*h], k1u[3*h], 0.f);
        s1 = dot2u(qh[3*h+1], k1u[3*h+1], s1);
        s1 = dot2u(qh[3*h+2], k1u[3*h+2], s1);
        p0[h] = exp2fast(s0);
        p1[h] = exp2fast(s1);
        lsum[h] += p0[h] + p1[h];
      }
      const unsigned int* vr = Vb + kp * VSTRIDE;
      u32x4 va = *(const u32x4*)(vr);
      u32x4 vbb = *(const u32x4*)(vr + 4);
      u32x4 vc = *(const u32x4*)(vr + 8);
      u32x4 vd = *(const u32x4*)(vr + 12);
      u32x4 ve = *(const u32x4*)(vr + 16);
      u32x4 vf = *(const u32x4*)(vr + 20);
      unsigned int vpu[24] = {va[0],va[1],va[2],va[3], vbb[0],vbb[1],vbb[2],vbb[3],
                              vc[0],vc[1],vc[2],vc[3], vd[0],vd[1],vd[2],vd[3],
                              ve[0],ve[1],ve[2],ve[3], vf[0],vf[1],vf[2],vf[3]};
      #pragma unroll
      for (int h = 0; h < 4; ++h) {
        h2 pp = pkh2(p0[h], p1[h]);
        #pragma unroll
        for (int i = 0; i < 6; ++i)
          acc_o[6*h+i] = dot2u(pp, vpu[6*h+i], acc_o[6*h+i]);
      }
    }
    #pragma unroll
    for (int h = 0; h < 4; ++h) {
      const float inv = 1.0f / lsum[h];
      #pragma unroll
      for (int dh = 0; dh < 6; ++dh) acc_o[6*h+dh] *= inv;
    }
    // ---- O-proj + residual + LN1 ----
    const float* BO = bo + layer * 24;
    h2 oh[12];
    #pragma unroll
    for (int i = 0; i < 12; ++i) oh[i] = pkh2(acc_o[2*i], acc_o[2*i+1]);
    float xo[24];
    #pragma unroll
    for (int j = 0; j < 24; ++j) {
      float s = BO[j];
      const unsigned int* wr = Woh + j * 12;
      #pragma unroll
      for (int kd = 0; kd < 12; ++kd) s = dot2u(oh[kd], wr[kd], s);
      xo[j] = x[j] + s;
    }
    float mean = 0.f;
    #pragma unroll
    for (int j = 0; j < 24; ++j) mean += xo[j];
    mean *= (1.f / 24.f);
    float var = 0.f;
    #pragma unroll
    for (int j = 0; j < 24; ++j) { const float dd = xo[j] - mean; var = fmaf(dd, dd, var); }
    var *= (1.f / 24.f);
    const float rstd = rsqrtf(var + 1e-5f);
    const float* G1 = lg1 + layer * 24;
    const float* Bl1 = lb1 + layer * 24;
    float xn[24];
    #pragma unroll
    for (int j = 0; j < 24; ++j) xn[j] = (xo[j] - mean) * rstd * G1[j] + Bl1[j];
    // ---- FFN via dot2 (fw2 transposed-pair layout) ----
    const float* Bf1 = fb1 + layer * 96;
    const float* Bf2 = fb2 + layer * 24;
    h2 xnh[12];
    #pragma unroll
    for (int i = 0; i < 12; ++i) xnh[i] = pkh2(xn[2*i], xn[2*i+1]);
    float y[24];
    #pragma unroll
    for (int d = 0; d < 24; ++d) y[d] = xn[d] + Bf2[d];
    #pragma unroll 1
    for (int jp = 0; jp < 48; ++jp) {
      float sa = Bf1[2*jp], sb = Bf1[2*jp+1];
      const unsigned int* w1 = F1h + (2*jp) * 12;
      #pragma unroll
      for (int kd = 0; kd < 12; ++kd) {
        sa = dot2u(xnh[kd], w1[kd], sa);
        sb = dot2u(xnh[kd], w1[12 + kd], sb);
      }
      sa = fmaxf(sa, 0.f);
      sb = fmaxf(sb, 0.f);
      h2 sp = pkh2(sa, sb);
      const unsigned int* w2 = F2t + jp * 24;
      #pragma unroll
      for (int d = 0; d < 24; ++d) y[d] = dot2u(sp, w2[d], y[d]);
    }
    // ---- LN2 ----
    float mean2 = 0.f;
    #pragma unroll
    for (int j = 0; j < 24; ++j) mean2 += y[j];
    mean2 *= (1.f / 24.f);
    float var2 = 0.f;
    #pragma unroll
    for (int j = 0; j < 24; ++j) { const float dd = y[j] - mean2; var2 = fmaf(dd, dd, var2); }
    var2 *= (1.f / 24.f);
    const float rstd2 = rsqrtf(var2 + 1e-5f);
    const float* G2 = lg2 + layer * 24;
    const float* Bl2 = lb2 + layer * 24;
    #pragma unroll
    for (int j = 0; j < 24; ++j) xf[j] = (y[j] - mean2) * rstd2 * G2[j] + Bl2[j];
    if (layer == 0) {
      #pragma unroll
      for (int j = 0; j < 24; ++j) x[j] = xf[j];
    }
    __syncthreads();   // attention reads done before next layer's K/V writes
  }
  if (storeOK) {
    float* op = out + (size_t)b * 1968 + t * 24;
    #pragma unroll
    for (int d4 = 0; d4 < 6; ++d4) {
      f32x4 v = { xf[4*d4], xf[4*d4+1], xf[4*d4+2], xf[4*d4+3] };
      *(f32x4*)(op + 4 * d4) = v;
    }
  }
}

// ---------------------------------------------------------------------------
extern "C" void kernel_launch(void* const* d_in, const int* in_sizes, int n_in,
                              void* d_out, int out_size, void* d_ws, size_t ws_size,
                              hipStream_t stream) {
  const float* gene    = (const float*)d_in[0];
  const float* protein = (const float*)d_in[1];
  const float* pathway = (const float*)d_in[2];
  const float* misc    = (const float*)d_in[3];
  const float* gw1 = (const float*)d_in[4];
  const float* gb1 = (const float*)d_in[5];
  const float* gg1 = (const float*)d_in[6];
  const float* gbb1= (const float*)d_in[7];
  const float* gw2 = (const float*)d_in[8];
  const float* gb2 = (const float*)d_in[9];
  const float* gg2 = (const float*)d_in[10];
  const float* gbb2= (const float*)d_in[11];
  const float* gw3 = (const float*)d_in[12];
  const float* gb3 = (const float*)d_in[13];
  const float* pw1 = (const float*)d_in[14];
  const float* pb1 = (const float*)d_in[15];
  const float* pg1 = (const float*)d_in[16];
  const float* pbb1= (const float*)d_in[17];
  const float* pw2 = (const float*)d_in[18];
  const float* pb2 = (const float*)d_in[19];
  const float* pg2 = (const float*)d_in[20];
  const float* pbb2= (const float*)d_in[21];
  const float* pw3 = (const float*)d_in[22];
  const float* pb3 = (const float*)d_in[23];
  const float* wqkv= (const float*)d_in[24];
  const float* bqkv= (const float*)d_in[25];
  const float* wo  = (const float*)d_in[26];
  const float* bo  = (const float*)d_in[27];
  const float* lg1 = (const float*)d_in[28];
  const float* lb1 = (const float*)d_in[29];
  const float* fw1 = (const float*)d_in[30];
  const float* fb1 = (const float*)d_in[31];
  const float* fw2 = (const float*)d_in[32];
  const float* fb2 = (const float*)d_in[33];
  const float* lg2 = (const float*)d_in[34];
  const float* lb2 = (const float*)d_in[35];

  const int B = in_sizes[0] / 5000;   // 8192

  float* bufA = (float*)d_ws;                          // [B,512]
  float* bufB = bufA + (size_t)B * 512;                // [B,512]
  float* logits_g = bufB + (size_t)B * 512;            // [B,82]
  float* logits_p = logits_g + (size_t)B * 82;         // [B,82]
  float* w_sum    = logits_p + (size_t)B * 82;         // [B,82]
  unsigned int* whb = (unsigned int*)(w_sum + (size_t)B * 82);  // 6912 dwords

  dim3 blk(256);
  // encoder weight pre-pack (f32 -> packed f16 pairs)
  pack_weights_kernel<<<dim3(27), blk, 0, stream>>>(wqkv, wo, fw1, fw2, whb);
  // gene adapter: 5000 -> 512 -> 256 -> 82
  gemm_bias_kernel<<<dim3(B / 64, 4), blk, 0, stream>>>(gene, gw1, gb1, bufA, B, 512, 5000);
  ln_gelu_kernel<<<dim3(B), blk, 0, stream>>>(bufA, gg1, gbb1, bufB, 512);
  gemm_bias_kernel<<<dim3(B / 64, 2), blk, 0, stream>>>(bufB, gw2, gb2, bufA, B, 256, 512);
  ln_gelu_kernel<<<dim3(B), blk, 0, stream>>>(bufA, gg2, gbb2, bufB, 256);
  gemm_bias_kernel<<<dim3(B / 64, 1), blk, 0, stream>>>(bufB, gw3, gb3, logits_g, B, 82, 256);
  // protein adapter: 226 -> 512 -> 256 -> 82
  gemm_bias_kernel<<<dim3(B / 64, 4), blk, 0, stream>>>(protein, pw1, pb1, bufA, B, 512, 226);
  ln_gelu_kernel<<<dim3(B), blk, 0, stream>>>(bufA, pg1, pbb1, bufB, 512);
  gemm_bias_kernel<<<dim3(B / 64, 2), blk, 0, stream>>>(bufB, pw2, pb2, bufA, B, 256, 512);
  ln_gelu_kernel<<<dim3(B), blk, 0, stream>>>(bufA, pg2, pbb2, bufB, 256);
  gemm_bias_kernel<<<dim3(B / 64, 1), blk, 0, stream>>>(bufB, pw3, pb3, logits_p, B, 82, 256);
  // combine softmaxes
  softmax2_kernel<<<dim3((B + 3) / 4), blk, 0, stream>>>(logits_g, logits_p, w_sum, B);
  // fused 2-layer transformer encoder
  encoder_kernel<<<dim3((B + 2) / 3), blk, 0, stream>>>(w_sum, pathway, misc,
      whb, bqkv, bo, lg1, lb1, fb1, fb2, lg2, lb2,
      (float*)d_out, B);
}

// Round 5
// 559.886 us; speedup vs baseline: 2.8537x; 1.5891x over previous
//
#include <hip/hip_runtime.h>
#include <hip/hip_bf16.h>
#include <math.h>

typedef __attribute__((ext_vector_type(4))) float f32x4;
typedef __attribute__((ext_vector_type(8))) short s16x8;
typedef __attribute__((ext_vector_type(4))) short s16x4;
typedef __attribute__((ext_vector_type(4))) unsigned int u32x4;
typedef __attribute__((ext_vector_type(2))) unsigned int u32x2;
typedef _Float16 h2 __attribute__((ext_vector_type(2)));

static __device__ __forceinline__ unsigned short f2bf(float f) {
  unsigned int u = __builtin_bit_cast(unsigned int, f);
  u += 0x7FFFu + ((u >> 16) & 1u);           // RNE
  return (unsigned short)(u >> 16);
}
static __device__ __forceinline__ unsigned int pk2bf(float a, float b) {
  return (unsigned int)f2bf(a) | ((unsigned int)f2bf(b) << 16);
}
static __device__ __forceinline__ float gelu_exact(float x) {
  return 0.5f * x * (1.0f + erff(x * 0.7071067811865475f));
}
static __device__ __forceinline__ h2 pkh2(float a, float b) {
#if __has_builtin(__builtin_amdgcn_cvt_pkrtz)
  return __builtin_bit_cast(h2, __builtin_amdgcn_cvt_pkrtz(a, b));
#else
  h2 r; r[0] = (_Float16)a; r[1] = (_Float16)b; return r;
#endif
}
static __device__ __forceinline__ float dot2u(h2 a, unsigned int b, float c) {
  h2 bh = __builtin_bit_cast(h2, b);
#if __has_builtin(__builtin_amdgcn_fdot2)
  return __builtin_amdgcn_fdot2(a, bh, c, false);
#else
  return fmaf((float)a[0], (float)bh[0], fmaf((float)a[1], (float)bh[1], c));
#endif
}
static __device__ __forceinline__ float exp2fast(float x) {
#if __has_builtin(__builtin_amdgcn_exp2f)
  return __builtin_amdgcn_exp2f(x);
#else
  return exp2f(x);
#endif
}
// async global->LDS 16B (dest = wave-uniform base + lane*16, layout linear)
static __device__ __forceinline__ void gll16(const void* g, void* l) {
#if __has_builtin(__builtin_amdgcn_global_load_lds)
  __builtin_amdgcn_global_load_lds((__attribute__((address_space(1))) void*)(void*)g,
                                   (__attribute__((address_space(3))) void*)l, 16, 0, 0);
#else
  *(u32x4*)l = *(const u32x4*)g;
#endif
}

// ===========================================================================
// NEW PATH: tiled+swizzled bf16 GEMM pipeline
// Buffer layout: sequence of 64x64-bf16 tiles [tm][tk], each 8192 B.
// Within a tile, 16B-block (r, cb) holds logical row r, col-block cb^(r&7)
// (XOR swizzle baked into global layout -> linear global_load_lds staging
//  lands swizzled in LDS -> conflict-free ds_read_b128 frag reads).
// ===========================================================================

// fp32 [Msrc][Ksrc] -> tiled bf16 [ceil? Mpad/64 tiles][TK tiles], zero-padded
__global__ __launch_bounds__(256)
void convert_tile_kernel(const float* __restrict__ src, unsigned short* __restrict__ dst,
                         int Msrc, int Ksrc, int TK, int total16) {
  const int id = blockIdx.x * 256 + threadIdx.x;
  if (id >= total16) return;
  const int j = id & 511;
  const int tile = id >> 9;
  const int tk = tile % TK;
  const int tmm = tile / TK;
  const int r = j >> 3, cb = j & 7;
  const int lcb = cb ^ (r & 7);
  const int row = tmm * 64 + r;
  const int col = tk * 64 + lcb * 8;
  float v[8];
  #pragma unroll
  for (int i = 0; i < 8; ++i) v[i] = 0.f;
  if (row < Msrc) {
    const size_t base = (size_t)row * Ksrc + col;
    if (col + 8 <= Ksrc && ((base & 3) == 0)) {
      f32x4 a = *(const f32x4*)(src + base);
      f32x4 b = *(const f32x4*)(src + base + 4);
      v[0]=a[0];v[1]=a[1];v[2]=a[2];v[3]=a[3];
      v[4]=b[0];v[5]=b[1];v[6]=b[2];v[7]=b[3];
    } else {
      #pragma unroll
      for (int i = 0; i < 8; ++i) if (col + i < Ksrc) v[i] = src[base + i];
    }
  }
  u32x4 o = { pk2bf(v[0],v[1]), pk2bf(v[2],v[3]), pk2bf(v[4],v[5]), pk2bf(v[6],v[7]) };
  *(u32x4*)(dst + (size_t)id * 8) = o;
}

// GEMM: C[M, Ntrue] = At (tiled bf16) @ Bt (tiled bf16, N-major rows)^T + bias
// BM=64 BN=128 BK=64, 256 thr = 4 waves (2x2). XCD-grouped block mapping.
__global__ __launch_bounds__(256, 4)
void gemm_bf16t_kernel(const unsigned short* __restrict__ At, const unsigned short* __restrict__ Bt,
                       const float* __restrict__ bias, float* __restrict__ C,
                       int NT, int KT, int Ntrue, int Nld) {
  __shared__ unsigned short As[4096];   //  8 KB: 64x64
  __shared__ unsigned short Bs[8192];   // 16 KB: 2 tiles (128 cols)
  const int tid = threadIdx.x;
  const int lane = tid & 63;
  const int wid = tid >> 6;
  const int wm = wid >> 1, wn = wid & 1;
  const int lr = lane & 15;
  const int lkb = ((lane >> 4) & 3) * 16;       // byte offset of 8-elem k-group
  const int l = blockIdx.x;
  const int xcd = l & 7;
  const int kl = l >> 3;
  const int nb = kl % NT;
  const int tm = (kl / NT) * 8 + xcd;
  const size_t abase = (size_t)tm * KT * 4096;
  const size_t bbase0 = (size_t)(2 * nb) * KT * 4096;
  const size_t bbase1 = (size_t)(2 * nb + 1) * KT * 4096;

  f32x4 acc[2][4];
  #pragma unroll
  for (int m = 0; m < 2; ++m)
    #pragma unroll
    for (int n = 0; n < 4; ++n) acc[m][n] = (f32x4){0.f,0.f,0.f,0.f};

  for (int tk = 0; tk < KT; ++tk) {
    __syncthreads();
    const unsigned short* at = At + abase + (size_t)tk * 4096;
    const unsigned short* b0 = Bt + bbase0 + (size_t)tk * 4096;
    const unsigned short* b1 = Bt + bbase1 + (size_t)tk * 4096;
    gll16(at + tid * 8,        (char*)As + tid * 16);
    gll16(at + 2048 + tid * 8, (char*)As + 4096 + tid * 16);
    gll16(b0 + tid * 8,        (char*)Bs + tid * 16);
    gll16(b0 + 2048 + tid * 8, (char*)Bs + 4096 + tid * 16);
    gll16(b1 + tid * 8,        (char*)Bs + 8192 + tid * 16);
    gll16(b1 + 2048 + tid * 8, (char*)Bs + 12288 + tid * 16);
    __syncthreads();
    #pragma unroll
    for (int kk = 0; kk < 2; ++kk) {
      const int kb = (kk * 64 + lkb) ^ ((lr & 7) << 4);
      s16x8 af[2], bfr[4];
      #pragma unroll
      for (int m = 0; m < 2; ++m) {
        const int r = wm * 32 + m * 16 + lr;
        af[m] = *(const s16x8*)((const char*)As + r * 128 + kb);
      }
      #pragma unroll
      for (int n = 0; n < 4; ++n) {
        const int c = wn * 64 + n * 16 + lr;
        bfr[n] = *(const s16x8*)((const char*)Bs + (c >> 6) * 8192 + (c & 63) * 128 + kb);
      }
      #pragma unroll
      for (int m = 0; m < 2; ++m)
        #pragma unroll
        for (int n = 0; n < 4; ++n)
          acc[m][n] = __builtin_amdgcn_mfma_f32_16x16x32_bf16(af[m], bfr[n], acc[m][n], 0, 0, 0);
    }
  }
  const int crow = (lane >> 4) * 4;
  #pragma unroll
  for (int m = 0; m < 2; ++m) {
    const int row = tm * 64 + wm * 32 + m * 16 + crow;
    #pragma unroll
    for (int n = 0; n < 4; ++n) {
      const int col = nb * 128 + wn * 64 + n * 16 + lr;
      if (col < Ntrue) {
        const float bv = bias[col];
        #pragma unroll
        for (int i = 0; i < 4; ++i)
          C[(size_t)(row + i) * Nld + col] = acc[m][n][i] + bv;
      }
    }
  }
}

// LN + GELU, fp32 in -> tiled-swizzled bf16 out. One wave per row.
__global__ __launch_bounds__(256)
void ln_gelu_b16t_kernel(const float* __restrict__ X, const float* __restrict__ g,
                         const float* __restrict__ bta, unsigned short* __restrict__ Y,
                         int N, int TK) {
  const int lane = threadIdx.x & 63;
  const int row = blockIdx.x * 4 + (threadIdx.x >> 6);
  const int tmv = row >> 6, r = row & 63;
  const float* xr = X + (size_t)row * N;
  if (N == 512) {
    const int c0 = lane * 8;
    f32x4 a = *(const f32x4*)(xr + c0);
    f32x4 b = *(const f32x4*)(xr + c0 + 4);
    float s = a[0]+a[1]+a[2]+a[3]+b[0]+b[1]+b[2]+b[3];
    float ss = a[0]*a[0]+a[1]*a[1]+a[2]*a[2]+a[3]*a[3]+b[0]*b[0]+b[1]*b[1]+b[2]*b[2]+b[3]*b[3];
    #pragma unroll
    for (int off = 1; off < 64; off <<= 1) { s += __shfl_xor(s, off); ss += __shfl_xor(ss, off); }
    const float mean = s * (1.f/512.f);
    const float var = ss * (1.f/512.f) - mean * mean;
    const float rstd = rsqrtf(var + 1e-5f);
    float z[8];
    #pragma unroll
    for (int i = 0; i < 4; ++i) z[i]   = gelu_exact((a[i]-mean)*rstd*g[c0+i]   + bta[c0+i]);
    #pragma unroll
    for (int i = 0; i < 4; ++i) z[4+i] = gelu_exact((b[i]-mean)*rstd*g[c0+4+i] + bta[c0+4+i]);
    const int tk = lane >> 3, lcb = lane & 7;
    const size_t d16 = ((size_t)(tmv * TK + tk) << 9) + (r << 3) + (lcb ^ (r & 7));
    u32x4 o = { pk2bf(z[0],z[1]), pk2bf(z[2],z[3]), pk2bf(z[4],z[5]), pk2bf(z[6],z[7]) };
    *(u32x4*)(Y + d16 * 8) = o;
  } else {  // N == 256
    const int c0 = lane * 4;
    f32x4 a = *(const f32x4*)(xr + c0);
    float s = a[0]+a[1]+a[2]+a[3];
    float ss = a[0]*a[0]+a[1]*a[1]+a[2]*a[2]+a[3]*a[3];
    #pragma unroll
    for (int off = 1; off < 64; off <<= 1) { s += __shfl_xor(s, off); ss += __shfl_xor(ss, off); }
    const float mean = s * (1.f/256.f);
    const float var = ss * (1.f/256.f) - mean * mean;
    const float rstd = rsqrtf(var + 1e-5f);
    float z[4];
    #pragma unroll
    for (int i = 0; i < 4; ++i) z[i] = gelu_exact((a[i]-mean)*rstd*g[c0+i] + bta[c0+i]);
    const int tk = lane >> 4, lcb = (lane >> 1) & 7, half = lane & 1;
    const size_t d16 = ((size_t)(tmv * TK + tk) << 9) + (r << 3) + (lcb ^ (r & 7));
    u32x2 o = { pk2bf(z[0],z[1]), pk2bf(z[2],z[3]) };
    *(u32x2*)(Y + d16 * 8 + half * 4) = o;
  }
}

// ===========================================================================
// FALLBACK PATH kernels (round-4, verified) + shared kernels
// ===========================================================================
#define GBM 64
#define GBN 128
#define GBK 64
#define GLDS 72

__global__ __launch_bounds__(256, 2)
void gemm_bias_kernel(const float* __restrict__ A, const float* __restrict__ Bw,
                      const float* __restrict__ bias, float* __restrict__ C,
                      int M, int N, int K) {
  __shared__ short As[GBM * GLDS];
  __shared__ short Bs[GBN * GLDS];
  const int tid = threadIdx.x;
  const int lane = tid & 63;
  const int wid = tid >> 6;
  const int wm = wid >> 1;
  const int wn = wid & 1;
  const int m0 = blockIdx.x * GBM;
  const int n0 = blockIdx.y * GBN;
  const int lr = lane & 15;
  const int lk = (lane >> 4) * 8;
  const bool kAligned = ((K & 3) == 0);
  f32x4 acc[2][4];
  #pragma unroll
  for (int i = 0; i < 2; ++i)
    #pragma unroll
    for (int j = 0; j < 4; ++j) acc[i][j] = (f32x4){0.f, 0.f, 0.f, 0.f};
  for (int k0 = 0; k0 < K; k0 += GBK) {
    __syncthreads();
    const bool fullK = kAligned && (k0 + GBK <= K);
    #pragma unroll
    for (int pass = 0; pass < 4; ++pass) {
      const int f = pass * 1024 + tid * 4;
      const int r = f >> 6, c = f & 63;
      f32x4 v = (f32x4){0.f, 0.f, 0.f, 0.f};
      const float* src = A + (size_t)(m0 + r) * K + (k0 + c);
      if (fullK) v = *(const f32x4*)src;
      else {
        #pragma unroll
        for (int i = 0; i < 4; ++i) if (k0 + c + i < K) v[i] = src[i];
      }
      s16x4 sv = { (short)f2bf(v[0]), (short)f2bf(v[1]), (short)f2bf(v[2]), (short)f2bf(v[3]) };
      *(s16x4*)&As[r * GLDS + c] = sv;
    }
    #pragma unroll
    for (int pass = 0; pass < 8; ++pass) {
      const int f = pass * 1024 + tid * 4;
      const int r = f >> 6, c = f & 63;
      f32x4 v = (f32x4){0.f, 0.f, 0.f, 0.f};
      if (n0 + r < N) {
        const float* src = Bw + (size_t)(n0 + r) * K + (k0 + c);
        if (fullK) v = *(const f32x4*)src;
        else {
          #pragma unroll
          for (int i = 0; i < 4; ++i) if (k0 + c + i < K) v[i] = src[i];
        }
      }
      s16x4 sv = { (short)f2bf(v[0]), (short)f2bf(v[1]), (short)f2bf(v[2]), (short)f2bf(v[3]) };
      *(s16x4*)&Bs[r * GLDS + c] = sv;
    }
    __syncthreads();
    #pragma unroll
    for (int kk = 0; kk < GBK; kk += 32) {
      s16x8 af[2], bfr[4];
      #pragma unroll
      for (int m = 0; m < 2; ++m)
        af[m] = *(const s16x8*)&As[(wm * 32 + m * 16 + lr) * GLDS + kk + lk];
      #pragma unroll
      for (int n = 0; n < 4; ++n)
        bfr[n] = *(const s16x8*)&Bs[(wn * 64 + n * 16 + lr) * GLDS + kk + lk];
      #pragma unroll
      for (int m = 0; m < 2; ++m)
        #pragma unroll
        for (int n = 0; n < 4; ++n)
          acc[m][n] = __builtin_amdgcn_mfma_f32_16x16x32_bf16(af[m], bfr[n], acc[m][n], 0, 0, 0);
    }
  }
  const int crow = (lane >> 4) * 4;
  #pragma unroll
  for (int m = 0; m < 2; ++m) {
    const int row = m0 + wm * 32 + m * 16 + crow;
    #pragma unroll
    for (int n = 0; n < 4; ++n) {
      const int col = n0 + wn * 64 + n * 16 + lr;
      if (col < N) {
        const float bv = bias[col];
        #pragma unroll
        for (int i = 0; i < 4; ++i)
          C[(size_t)(row + i) * N + col] = acc[m][n][i] + bv;
      }
    }
  }
}

__global__ __launch_bounds__(256)
void ln_gelu_kernel(const float* __restrict__ X, const float* __restrict__ g,
                    const float* __restrict__ bta, float* __restrict__ Y, int N) {
  const int row = blockIdx.x;
  const float* xr = X + (size_t)row * N;
  float* yr = Y + (size_t)row * N;
  const int tid = threadIdx.x;
  const float e0 = xr[tid];
  float e1 = 0.f;
  const bool two = (N > 256);
  if (two) e1 = xr[tid + 256];
  float s = e0 + e1;
  float ss = e0 * e0 + e1 * e1;
  #pragma unroll
  for (int off = 1; off < 64; off <<= 1) { s += __shfl_xor(s, off); ss += __shfl_xor(ss, off); }
  __shared__ float red[8];
  const int w = tid >> 6;
  if ((tid & 63) == 0) { red[w] = s; red[4 + w] = ss; }
  __syncthreads();
  s  = red[0] + red[1] + red[2] + red[3];
  ss = red[4] + red[5] + red[6] + red[7];
  const float invN = 1.0f / (float)N;
  const float mean = s * invN;
  const float var = ss * invN - mean * mean;
  const float rstd = rsqrtf(var + 1e-5f);
  { const float z = (e0 - mean) * rstd * g[tid] + bta[tid]; yr[tid] = gelu_exact(z); }
  if (two) { const float z = (e1 - mean) * rstd * g[tid + 256] + bta[tid + 256]; yr[tid + 256] = gelu_exact(z); }
}

__global__ __launch_bounds__(256)
void softmax2_kernel(const float* __restrict__ la, const float* __restrict__ lp,
                     float* __restrict__ w, int B) {
  const int wid = threadIdx.x >> 6;
  const int lane = threadIdx.x & 63;
  const int row = blockIdx.x * 4 + wid;
  if (row >= B) return;
  const bool has2 = (lane < 18);
  const float* a = la + (size_t)row * 82;
  const float* p = lp + (size_t)row * 82;
  float a0 = a[lane], a1 = has2 ? a[64 + lane] : -1e30f;
  float m = fmaxf(a0, a1);
  #pragma unroll
  for (int off = 1; off < 64; off <<= 1) m = fmaxf(m, __shfl_xor(m, off));
  float ea0 = __expf(a0 - m);
  float ea1 = has2 ? __expf(a1 - m) : 0.f;
  float sa = ea0 + ea1;
  #pragma unroll
  for (int off = 1; off < 64; off <<= 1) sa += __shfl_xor(sa, off);
  float p0 = p[lane], p1 = has2 ? p[64 + lane] : -1e30f;
  float mp = fmaxf(p0, p1);
  #pragma unroll
  for (int off = 1; off < 64; off <<= 1) mp = fmaxf(mp, __shfl_xor(mp, off));
  float ep0 = __expf(p0 - mp);
  float ep1 = has2 ? __expf(p1 - mp) : 0.f;
  float sp = ep0 + ep1;
  #pragma unroll
  for (int off = 1; off < 64; off <<= 1) sp += __shfl_xor(sp, off);
  const float ia = 1.0f / sa, ip = 1.0f / sp;
  w[(size_t)row * 82 + lane] = ea0 * ia + ep0 * ip;
  if (has2) w[(size_t)row * 82 + 64 + lane] = ea1 * ia + ep1 * ip;
}

__global__ __launch_bounds__(256)
void pack_weights_kernel(const float* __restrict__ wqkv, const float* __restrict__ wo,
                         const float* __restrict__ fw1, const float* __restrict__ fw2,
                         unsigned int* __restrict__ dst) {
  const int i = blockIdx.x * 256 + threadIdx.x;
  if (i >= 6912) return;
  float a, b;
  if (i < 1728)      { a = wqkv[2 * i];            b = wqkv[2 * i + 1]; }
  else if (i < 2304) { int j = i - 1728; a = wo[2 * j];  b = wo[2 * j + 1]; }
  else if (i < 4608) { int j = i - 2304; a = fw1[2 * j]; b = fw1[2 * j + 1]; }
  else {
    int j = i - 4608; int layer = j / 1152; int r = j % 1152;
    int jp = r / 24; int d = r % 24;
    const float* s = fw2 + layer * 2304 + d * 96 + 2 * jp;
    a = s[0]; b = s[1];
  }
  unsigned short lo = __builtin_bit_cast(unsigned short, (_Float16)a);
  unsigned short hi = __builtin_bit_cast(unsigned short, (_Float16)b);
  dst[i] = (unsigned int)lo | ((unsigned int)hi << 16);
}

// ---------------------------------------------------------------------------
// Fused 2-layer encoder (round-4, verified)
// ---------------------------------------------------------------------------
#define VSTRIDE 28

__global__ __launch_bounds__(256, 4)
void encoder_kernel(const float* __restrict__ w_sum,
                    const float* __restrict__ pathway, const float* __restrict__ misc,
                    const unsigned int* __restrict__ whb,
                    const float* __restrict__ bqkv, const float* __restrict__ bo,
                    const float* __restrict__ lg1, const float* __restrict__ lb1,
                    const float* __restrict__ fb1, const float* __restrict__ fb2,
                    const float* __restrict__ lg2, const float* __restrict__ lb2,
                    float* __restrict__ out, int Btot) {
  __shared__ unsigned int Ks[247 * 12];
  __shared__ unsigned int Vs[124 * VSTRIDE];
  const int tid = threadIdx.x;
  const bool active = (tid < 246);
  const int rowW = active ? tid : 246;
  int ls = tid / 82; if (ls > 2) ls = 2;
  const int t = active ? (tid - ls * 82) : 0;
  const int vrow = active ? (ls * 41 + (t >> 1)) : 123;
  const int b = blockIdx.x * 3 + ls;
  const bool storeOK = active && (b < Btot);
  const int bb = (b < Btot) ? b : (Btot - 1);
  float x[24];
  {
    const float* trow = (t < 50) ? (pathway + t * 24) : (misc + (t - 50) * 24);
    const float wv = w_sum[(size_t)bb * 82 + t];
    #pragma unroll
    for (int i = 0; i < 6; ++i) {
      f32x4 v = *(const f32x4*)(trow + 4 * i);
      x[4*i+0] = wv * v[0]; x[4*i+1] = wv * v[1];
      x[4*i+2] = wv * v[2]; x[4*i+3] = wv * v[3];
    }
  }
  const float QS = 0.5889777913f;   // 1/sqrt(6) * log2(e)
  float xf[24];
  #pragma unroll 1
  for (int layer = 0; layer < 2; ++layer) {
    const unsigned int* Wqh = whb + layer * 864;
    const unsigned int* Woh = whb + 1728 + layer * 288;
    const unsigned int* F1h = whb + 2304 + layer * 1152;
    const unsigned int* F2t = whb + 4608 + layer * 1152;
    const float* Bq = bqkv + layer * 72;
    h2 xh[12];
    #pragma unroll
    for (int i = 0; i < 12; ++i) xh[i] = pkh2(x[2*i], x[2*i+1]);
    h2 qh[12];
    #pragma unroll
    for (int j2 = 0; j2 < 12; ++j2) {
      float s0 = Bq[2*j2], s1 = Bq[2*j2+1];
      const unsigned int* w0 = Wqh + (2*j2) * 12;
      #pragma unroll
      for (int kd = 0; kd < 12; ++kd) { s0 = dot2u(xh[kd], w0[kd], s0); s1 = dot2u(xh[kd], w0[12 + kd], s1); }
      qh[j2] = pkh2(s0 * QS, s1 * QS);
    }
    {
      unsigned int kpk[12];
      #pragma unroll
      for (int j2 = 0; j2 < 12; ++j2) {
        float s0 = Bq[24 + 2*j2], s1 = Bq[25 + 2*j2];
        const unsigned int* w0 = Wqh + (24 + 2*j2) * 12;
        #pragma unroll
        for (int kd = 0; kd < 12; ++kd) { s0 = dot2u(xh[kd], w0[kd], s0); s1 = dot2u(xh[kd], w0[12 + kd], s1); }
        kpk[j2] = __builtin_bit_cast(unsigned int, pkh2(s0, s1));
      }
      #pragma unroll
      for (int u = 0; u < 3; ++u)
        *(u32x4*)&Ks[rowW * 12 + 4*u] = (u32x4){kpk[4*u], kpk[4*u+1], kpk[4*u+2], kpk[4*u+3]};
      float vv[24];
      #pragma unroll
      for (int j2 = 0; j2 < 12; ++j2) {
        float s0 = Bq[48 + 2*j2], s1 = Bq[49 + 2*j2];
        const unsigned int* w0 = Wqh + (48 + 2*j2) * 12;
        #pragma unroll
        for (int kd = 0; kd < 12; ++kd) { s0 = dot2u(xh[kd], w0[kd], s0); s1 = dot2u(xh[kd], w0[12 + kd], s1); }
        vv[2*j2] = s0; vv[2*j2+1] = s1;
      }
      _Float16* vh = (_Float16*)Vs;
      const int vbase = vrow * (2 * VSTRIDE) + (t & 1);
      #pragma unroll
      for (int j = 0; j < 24; ++j) vh[vbase + 2*j] = (_Float16)vv[j];
    }
    __syncthreads();
    float acc_o[24];
    float lsum[4] = {0.f, 0.f, 0.f, 0.f};
    #pragma unroll
    for (int d = 0; d < 24; ++d) acc_o[d] = 0.f;
    const unsigned int* Kb = Ks + ls * 82 * 12;
    const unsigned int* Vb = Vs + ls * 41 * VSTRIDE;
    #pragma unroll 1
    for (int kp = 0; kp < 41; ++kp) {
      const unsigned int* kr = Kb + kp * 24;
      u32x4 ka = *(const u32x4*)(kr);
      u32x4 kbv = *(const u32x4*)(kr + 4);
      u32x4 kc = *(const u32x4*)(kr + 8);
      u32x4 kd_ = *(const u32x4*)(kr + 12);
      u32x4 ke = *(const u32x4*)(kr + 16);
      u32x4 kf = *(const u32x4*)(kr + 20);
      unsigned int k0u[12] = {ka[0],ka[1],ka[2],ka[3], kbv[0],kbv[1],kbv[2],kbv[3], kc[0],kc[1],kc[2],kc[3]};
      unsigned int k1u[12] = {kd_[0],kd_[1],kd_[2],kd_[3], ke[0],ke[1],ke[2],ke[3], kf[0],kf[1],kf[2],kf[3]};
      float p0[4], p1[4];
      #pragma unroll
      for (int h = 0; h < 4; ++h) {
        float s0 = dot2u(qh[3*h], k0u[3*h], 0.f);
        s0 = dot2u(qh[3*h+1], k0u[3*h+1], s0);
        s0 = dot2u(qh[3*h+2], k0u[3*h+2], s0);
        float s1 = dot2u(qh[3*h], k1u[3*h], 0.f);
        s1 = dot2u(qh[3*h+1], k1u[3*h+1], s1);
        s1 = dot2u(qh[3*h+2], k1u[3*h+2], s1);
        p0[h] = exp2fast(s0);
        p1[h] = exp2fast(s1);
        lsum[h] += p0[h] + p1[h];
      }
      const unsigned int* vr = Vb + kp * VSTRIDE;
      u32x4 va = *(const u32x4*)(vr);
      u32x4 vbb = *(const u32x4*)(vr + 4);
      u32x4 vc = *(const u32x4*)(vr + 8);
      u32x4 vd = *(const u32x4*)(vr + 12);
      u32x4 ve = *(const u32x4*)(vr + 16);
      u32x4 vf = *(const u32x4*)(vr + 20);
      unsigned int vpu[24] = {va[0],va[1],va[2],va[3], vbb[0],vbb[1],vbb[2],vbb[3],
                              vc[0],vc[1],vc[2],vc[3], vd[0],vd[1],vd[2],vd[3],
                              ve[0],ve[1],ve[2],ve[3], vf[0],vf[1],vf[2],vf[3]};
      #pragma unroll
      for (int h = 0; h < 4; ++h) {
        h2 pp = pkh2(p0[h], p1[h]);
        #pragma unroll
        for (int i = 0; i < 6; ++i)
          acc_o[6*h+i] = dot2u(pp, vpu[6*h+i], acc_o[6*h+i]);
      }
    }
    #pragma unroll
    for (int h = 0; h < 4; ++h) {
      const float inv = 1.0f / lsum[h];
      #pragma unroll
      for (int dh = 0; dh < 6; ++dh) acc_o[6*h+dh] *= inv;
    }
    const float* BO = bo + layer * 24;
    h2 oh[12];
    #pragma unroll
    for (int i = 0; i < 12; ++i) oh[i] = pkh2(acc_o[2*i], acc_o[2*i+1]);
    float xo[24];
    #pragma unroll
    for (int j = 0; j < 24; ++j) {
      float s = BO[j];
      const unsigned int* wr = Woh + j * 12;
      #pragma unroll
      for (int kd = 0; kd < 12; ++kd) s = dot2u(oh[kd], wr[kd], s);
      xo[j] = x[j] + s;
    }
    float mean = 0.f;
    #pragma unroll
    for (int j = 0; j < 24; ++j) mean += xo[j];
    mean *= (1.f / 24.f);
    float var = 0.f;
    #pragma unroll
    for (int j = 0; j < 24; ++j) { const float dd = xo[j] - mean; var = fmaf(dd, dd, var); }
    var *= (1.f / 24.f);
    const float rstd = rsqrtf(var + 1e-5f);
    const float* G1 = lg1 + layer * 24;
    const float* Bl1 = lb1 + layer * 24;
    float xn[24];
    #pragma unroll
    for (int j = 0; j < 24; ++j) xn[j] = (xo[j] - mean) * rstd * G1[j] + Bl1[j];
    const float* Bf1 = fb1 + layer * 96;
    const float* Bf2 = fb2 + layer * 24;
    h2 xnh[12];
    #pragma unroll
    for (int i = 0; i < 12; ++i) xnh[i] = pkh2(xn[2*i], xn[2*i+1]);
    float y[24];
    #pragma unroll
    for (int d = 0; d < 24; ++d) y[d] = xn[d] + Bf2[d];
    #pragma unroll 1
    for (int jp = 0; jp < 48; ++jp) {
      float sa = Bf1[2*jp], sb = Bf1[2*jp+1];
      const unsigned int* w1 = F1h + (2*jp) * 12;
      #pragma unroll
      for (int kd = 0; kd < 12; ++kd) { sa = dot2u(xnh[kd], w1[kd], sa); sb = dot2u(xnh[kd], w1[12 + kd], sb); }
      sa = fmaxf(sa, 0.f);
      sb = fmaxf(sb, 0.f);
      h2 sp = pkh2(sa, sb);
      const unsigned int* w2 = F2t + jp * 24;
      #pragma unroll
      for (int d = 0; d < 24; ++d) y[d] = dot2u(sp, w2[d], y[d]);
    }
    float mean2 = 0.f;
    #pragma unroll
    for (int j = 0; j < 24; ++j) mean2 += y[j];
    mean2 *= (1.f / 24.f);
    float var2 = 0.f;
    #pragma unroll
    for (int j = 0; j < 24; ++j) { const float dd = y[j] - mean2; var2 = fmaf(dd, dd, var2); }
    var2 *= (1.f / 24.f);
    const float rstd2 = rsqrtf(var2 + 1e-5f);
    const float* G2 = lg2 + layer * 24;
    const float* Bl2 = lb2 + layer * 24;
    #pragma unroll
    for (int j = 0; j < 24; ++j) xf[j] = (y[j] - mean2) * rstd2 * G2[j] + Bl2[j];
    if (layer == 0) {
      #pragma unroll
      for (int j = 0; j < 24; ++j) x[j] = xf[j];
    }
    __syncthreads();
  }
  if (storeOK) {
    float* op = out + (size_t)b * 1968 + t * 24;
    #pragma unroll
    for (int d4 = 0; d4 < 6; ++d4) {
      f32x4 v = { xf[4*d4], xf[4*d4+1], xf[4*d4+2], xf[4*d4+3] };
      *(f32x4*)(op + 4 * d4) = v;
    }
  }
}

// ---------------------------------------------------------------------------
extern "C" void kernel_launch(void* const* d_in, const int* in_sizes, int n_in,
                              void* d_out, int out_size, void* d_ws, size_t ws_size,
                              hipStream_t stream) {
  const float* gene    = (const float*)d_in[0];
  const float* protein = (const float*)d_in[1];
  const float* pathway = (const float*)d_in[2];
  const float* misc    = (const float*)d_in[3];
  const float* gw1 = (const float*)d_in[4];
  const float* gb1 = (const float*)d_in[5];
  const float* gg1 = (const float*)d_in[6];
  const float* gbb1= (const float*)d_in[7];
  const float* gw2 = (const float*)d_in[8];
  const float* gb2 = (const float*)d_in[9];
  const float* gg2 = (const float*)d_in[10];
  const float* gbb2= (const float*)d_in[11];
  const float* gw3 = (const float*)d_in[12];
  const float* gb3 = (const float*)d_in[13];
  const float* pw1 = (const float*)d_in[14];
  const float* pb1 = (const float*)d_in[15];
  const float* pg1 = (const float*)d_in[16];
  const float* pbb1= (const float*)d_in[17];
  const float* pw2 = (const float*)d_in[18];
  const float* pb2 = (const float*)d_in[19];
  const float* pg2 = (const float*)d_in[20];
  const float* pbb2= (const float*)d_in[21];
  const float* pw3 = (const float*)d_in[22];
  const float* pb3 = (const float*)d_in[23];
  const float* wqkv= (const float*)d_in[24];
  const float* bqkv= (const float*)d_in[25];
  const float* wo  = (const float*)d_in[26];
  const float* bo  = (const float*)d_in[27];
  const float* lg1 = (const float*)d_in[28];
  const float* lb1 = (const float*)d_in[29];
  const float* fw1 = (const float*)d_in[30];
  const float* fb1 = (const float*)d_in[31];
  const float* fw2 = (const float*)d_in[32];
  const float* fb2 = (const float*)d_in[33];
  const float* lg2 = (const float*)d_in[34];
  const float* lb2 = (const float*)d_in[35];

  const int B = in_sizes[0] / 5000;   // 8192
  dim3 blk(256);

  // ---- new-path workspace layout ----
  size_t off = 0;
  auto take = [&](size_t bytes) { size_t r = off; off = (off + bytes + 255) & ~(size_t)255; return r; };
  const size_t o_geneB  = take((size_t)B * 5056 * 2);
  const size_t o_protB  = take((size_t)B * 256 * 2);
  const size_t o_gw1B   = take((size_t)512 * 5056 * 2);
  const size_t o_pw1B   = take((size_t)512 * 256 * 2);
  const size_t o_gw2B   = take((size_t)256 * 512 * 2);
  const size_t o_pw2B   = take((size_t)256 * 512 * 2);
  const size_t o_gw3B   = take((size_t)128 * 256 * 2);
  const size_t o_pw3B   = take((size_t)128 * 256 * 2);
  const size_t o_Cbuf   = take((size_t)B * 512 * 4);
  const size_t o_h1B    = take((size_t)B * 512 * 2);
  const size_t o_h2B    = take((size_t)B * 256 * 2);
  const size_t o_lg     = take((size_t)B * 82 * 4);
  const size_t o_lp     = take((size_t)B * 82 * 4);
  const size_t o_wsum   = take((size_t)B * 82 * 4);
  const size_t o_whb    = take((size_t)6912 * 4);
  const size_t need = off;

  if (need <= ws_size) {
    char* base = (char*)d_ws;
    unsigned short* geneB = (unsigned short*)(base + o_geneB);
    unsigned short* protB = (unsigned short*)(base + o_protB);
    unsigned short* gw1B  = (unsigned short*)(base + o_gw1B);
    unsigned short* pw1B  = (unsigned short*)(base + o_pw1B);
    unsigned short* gw2B  = (unsigned short*)(base + o_gw2B);
    unsigned short* pw2B  = (unsigned short*)(base + o_pw2B);
    unsigned short* gw3B  = (unsigned short*)(base + o_gw3B);
    unsigned short* pw3B  = (unsigned short*)(base + o_pw3B);
    float* Cbuf = (float*)(base + o_Cbuf);
    unsigned short* h1B = (unsigned short*)(base + o_h1B);
    unsigned short* h2B = (unsigned short*)(base + o_h2B);
    float* logits_g = (float*)(base + o_lg);
    float* logits_p = (float*)(base + o_lp);
    float* w_sum    = (float*)(base + o_wsum);
    unsigned int* whb = (unsigned int*)(base + o_whb);

    const int MT = B / 64;   // 128
    // converts (weights + inputs)
    pack_weights_kernel<<<dim3(27), blk, 0, stream>>>(wqkv, wo, fw1, fw2, whb);
    {
      int t16 = MT * 79 * 512;   // gene: [8192][5000->5056]
      convert_tile_kernel<<<dim3((t16 + 255) / 256), blk, 0, stream>>>(gene, geneB, B, 5000, 79, t16);
      t16 = MT * 4 * 512;        // protein: [8192][226->256]
      convert_tile_kernel<<<dim3((t16 + 255) / 256), blk, 0, stream>>>(protein, protB, B, 226, 4, t16);
      t16 = 8 * 79 * 512;
      convert_tile_kernel<<<dim3((t16 + 255) / 256), blk, 0, stream>>>(gw1, gw1B, 512, 5000, 79, t16);
      t16 = 8 * 4 * 512;
      convert_tile_kernel<<<dim3((t16 + 255) / 256), blk, 0, stream>>>(pw1, pw1B, 512, 226, 4, t16);
      t16 = 4 * 8 * 512;
      convert_tile_kernel<<<dim3((t16 + 255) / 256), blk, 0, stream>>>(gw2, gw2B, 256, 512, 8, t16);
      convert_tile_kernel<<<dim3((t16 + 255) / 256), blk, 0, stream>>>(pw2, pw2B, 256, 512, 8, t16);
      t16 = 2 * 4 * 512;
      convert_tile_kernel<<<dim3((t16 + 255) / 256), blk, 0, stream>>>(gw3, gw3B, 82, 256, 4, t16);
      convert_tile_kernel<<<dim3((t16 + 255) / 256), blk, 0, stream>>>(pw3, pw3B, 82, 256, 4, t16);
    }
    // gene chain
    gemm_bf16t_kernel<<<dim3(MT * 4), blk, 0, stream>>>(geneB, gw1B, gb1, Cbuf, 4, 79, 512, 512);
    ln_gelu_b16t_kernel<<<dim3(B / 4), blk, 0, stream>>>(Cbuf, gg1, gbb1, h1B, 512, 8);
    gemm_bf16t_kernel<<<dim3(MT * 2), blk, 0, stream>>>(h1B, gw2B, gb2, Cbuf, 2, 8, 256, 256);
    ln_gelu_b16t_kernel<<<dim3(B / 4), blk, 0, stream>>>(Cbuf, gg2, gbb2, h2B, 256, 4);
    gemm_bf16t_kernel<<<dim3(MT * 1), blk, 0, stream>>>(h2B, gw3B, gb3, logits_g, 1, 4, 82, 82);
    // protein chain
    gemm_bf16t_kernel<<<dim3(MT * 4), blk, 0, stream>>>(protB, pw1B, pb1, Cbuf, 4, 4, 512, 512);
    ln_gelu_b16t_kernel<<<dim3(B / 4), blk, 0, stream>>>(Cbuf, pg1, pbb1, h1B, 512, 8);
    gemm_bf16t_kernel<<<dim3(MT * 2), blk, 0, stream>>>(h1B, pw2B, pb2, Cbuf, 2, 8, 256, 256);
    ln_gelu_b16t_kernel<<<dim3(B / 4), blk, 0, stream>>>(Cbuf, pg2, pbb2, h2B, 256, 4);
    gemm_bf16t_kernel<<<dim3(MT * 1), blk, 0, stream>>>(h2B, pw3B, pb3, logits_p, 1, 4, 82, 82);
    // combine + encoder
    softmax2_kernel<<<dim3((B + 3) / 4), blk, 0, stream>>>(logits_g, logits_p, w_sum, B);
    encoder_kernel<<<dim3((B + 2) / 3), blk, 0, stream>>>(w_sum, pathway, misc,
        whb, bqkv, bo, lg1, lb1, fb1, fb2, lg2, lb2, (float*)d_out, B);
    return;
  }

  // ---- fallback: round-4 verified path ----
  float* bufA = (float*)d_ws;
  float* bufB = bufA + (size_t)B * 512;
  float* logits_g = bufB + (size_t)B * 512;
  float* logits_p = logits_g + (size_t)B * 82;
  float* w_sum    = logits_p + (size_t)B * 82;
  unsigned int* whb = (unsigned int*)(w_sum + (size_t)B * 82);

  pack_weights_kernel<<<dim3(27), blk, 0, stream>>>(wqkv, wo, fw1, fw2, whb);
  gemm_bias_kernel<<<dim3(B / 64, 4), blk, 0, stream>>>(gene, gw1, gb1, bufA, B, 512, 5000);
  ln_gelu_kernel<<<dim3(B), blk, 0, stream>>>(bufA, gg1, gbb1, bufB, 512);
  gemm_bias_kernel<<<dim3(B / 64, 2), blk, 0, stream>>>(bufB, gw2, gb2, bufA, B, 256, 512);
  ln_gelu_kernel<<<dim3(B), blk, 0, stream>>>(bufA, gg2, gbb2, bufB, 256);
  gemm_bias_kernel<<<dim3(B / 64, 1), blk, 0, stream>>>(bufB, gw3, gb3, logits_g, B, 82, 256);
  gemm_bias_kernel<<<dim3(B / 64, 4), blk, 0, stream>>>(protein, pw1, pb1, bufA, B, 512, 226);
  ln_gelu_kernel<<<dim3(B), blk, 0, stream>>>(bufA, pg1, pbb1, bufB, 512);
  gemm_bias_kernel<<<dim3(B / 64, 2), blk, 0, stream>>>(bufB, pw2, pb2, bufA, B, 256, 512);
  ln_gelu_kernel<<<dim3(B), blk, 0, stream>>>(bufA, pg2, pbb2, bufB, 256);
  gemm_bias_kernel<<<dim3(B / 64, 1), blk, 0, stream>>>(bufB, pw3, pb3, logits_p, B, 82, 256);
  softmax2_kernel<<<dim3((B + 3) / 4), blk, 0, stream>>>(logits_g, logits_p, w_sum, B);
  encoder_kernel<<<dim3((B + 2) / 3), blk, 0, stream>>>(w_sum, pathway, misc,
      whb, bqkv, bo, lg1, lb1, fb1, fb2, lg2, lb2, (float*)d_out, B);
}